// Round 8
// baseline (410.955 us; speedup 1.0000x reference)
//
#include <hip/hip_runtime.h>

#define BB 16
#define NN 1000
#define DD 256
#define LL 3
#define MAXNZ 256
#define MROWS (BB * NN)
#define SPLIT_SCALE 2048.0f
#define INV_SPLIT 4.8828125e-4f

typedef _Float16 f16x8 __attribute__((ext_vector_type(8)));
typedef _Float16 f16x2 __attribute__((ext_vector_type(2)));
typedef float f32x4 __attribute__((ext_vector_type(4)));

union H8 { f16x8 v; f16x2 p[4]; _Float16 h[8]; int4 i4; };

#if defined(__has_builtin)
#if __has_builtin(__builtin_amdgcn_fdot2)
#define HAS_FDOT2 1
#endif
#endif

__device__ __forceinline__ float dot2f(f16x2 a, f16x2 b, float c) {
#ifdef HAS_FDOT2
    return __builtin_amdgcn_fdot2(a, b, c, false);
#else
    return fmaf((float)a[0], (float)b[0], fmaf((float)a[1], (float)b[1], c));
#endif
}

// ---------------------------------------------------------------------------
// Kernel 0a: split+transpose the 10 weight matrices -> wt[mat][n][k] hi/lo.
// ---------------------------------------------------------------------------
__global__ __launch_bounds__(256) void convert_w(
    const float* __restrict__ W_list, const float* __restrict__ dense_W,
    const float* __restrict__ final_W,
    _Float16* __restrict__ wt_hi, _Float16* __restrict__ wt_lo)
{
    __shared__ float T[64][68];
    int blk = blockIdx.x;          // 10 mats * 16 tiles
    int mat = blk >> 4;
    int tile = blk & 15;
    int tk = (tile >> 2) * 64, tn = (tile & 3) * 64;
    const float* src = (mat < 3) ? (W_list + (size_t)mat * 65536)
                     : (mat < 9) ? (dense_W + (size_t)(mat - 3) * 65536)
                                 : final_W;
    int t = threadIdx.x;
    {
        int k = t >> 2, nc = (t & 3) * 16;
        const float* sp = src + (size_t)(tk + k) * 256 + tn + nc;
        *(float4*)&T[k][nc + 0]  = *(const float4*)(sp + 0);
        *(float4*)&T[k][nc + 4]  = *(const float4*)(sp + 4);
        *(float4*)&T[k][nc + 8]  = *(const float4*)(sp + 8);
        *(float4*)&T[k][nc + 12] = *(const float4*)(sp + 12);
    }
    __syncthreads();
    int n = t >> 2, kc = (t & 3) * 16;
    H8 hh0, hh1, ll0, ll1;
    #pragma unroll
    for (int i = 0; i < 16; ++i) {
        float x = T[kc + i][n];
        _Float16 hi = (_Float16)x;
        _Float16 lo = (_Float16)((x - (float)hi) * SPLIT_SCALE);
        if (i < 8) { hh0.h[i] = hi; ll0.h[i] = lo; }
        else       { hh1.h[i - 8] = hi; ll1.h[i - 8] = lo; }
    }
    size_t o = (size_t)mat * 65536 + (size_t)(tn + n) * 256 + tk + kc;
    *(int4*)(wt_hi + o)     = hh0.i4;
    *(int4*)(wt_hi + o + 8) = hh1.i4;
    *(int4*)(wt_lo + o)     = ll0.i4;
    *(int4*)(wt_lo + o + 8) = ll1.i4;
}

// ---------------------------------------------------------------------------
// Kernel 0b: split x_in fp32 -> hi/lo fp16 planes.
// ---------------------------------------------------------------------------
__global__ __launch_bounds__(256) void convert_x(
    const float* __restrict__ in, _Float16* __restrict__ hi,
    _Float16* __restrict__ lo)
{
    size_t gid = (size_t)blockIdx.x * 256 + threadIdx.x;
    const float* p = in + gid * 8;
    float4 a = *(const float4*)p;
    float4 b = *(const float4*)(p + 4);
    float xs[8] = {a.x, a.y, a.z, a.w, b.x, b.y, b.z, b.w};
    H8 hh, ll;
    #pragma unroll
    for (int i = 0; i < 8; ++i) {
        _Float16 h = (_Float16)xs[i];
        hh.h[i] = h;
        ll.h[i] = (_Float16)((xs[i] - (float)h) * SPLIT_SCALE);
    }
    *(int4*)(hi + gid * 8) = hh.i4;
    *(int4*)(lo + gid * 8) = ll.i4;
}

// ---------------------------------------------------------------------------
// Kernel 1: build sparse structure of A = prot_contacts + eye.
// ---------------------------------------------------------------------------
__global__ __launch_bounds__(256) void build_sparse(
    const float* __restrict__ contacts,
    int* __restrict__ idx, int* __restrict__ cnt, float* __restrict__ adiag)
{
    int wave = (int)((blockIdx.x * blockDim.x + threadIdx.x) >> 6);
    int lane = threadIdx.x & 63;
    if (wave >= MROWS) return;
    int b = wave / NN;
    int i = wave - b * NN;
    const float* row = contacts + (size_t)b * NN * NN + (size_t)i * NN;
    int* out = idx + (size_t)wave * MAXNZ;
    int count = 0;
    for (int j0 = 0; j0 < NN; j0 += 64) {
        int j = j0 + lane;
        float v = (j < NN) ? row[j] : 0.0f;
        bool p = (v != 0.0f) && (j != i);
        unsigned long long bal = __ballot(p);
        if (p) {
            int pre = __popcll(bal & ((1ull << lane) - 1ull));
            out[count + pre] = j;
        }
        count += __popcll(bal);
    }
    if (lane == 0) {
        cnt[wave] = count;
        adiag[wave] = row[i] + 1.0f;
    }
}

// ---------------------------------------------------------------------------
// Kernel 2: sparse attention aggregate v4 (round-6, known-good).
// 1 wave per row; 16-lane group holds full 256-dim row (8+8 halves/lane).
// 4 neighbors in flight; 2-deep index + 1-deep data pipeline. XCD-local rows.
// ---------------------------------------------------------------------------
__global__ __launch_bounds__(256) void sparse_agg(
    const _Float16* __restrict__ yhi,
    const _Float16* __restrict__ xhi, const _Float16* __restrict__ xlo,
    const int* __restrict__ idx, const int* __restrict__ cnt,
    const float* __restrict__ adiag,
    _Float16* __restrict__ ohi, _Float16* __restrict__ olo)
{
    int bid = blockIdx.x;
    int xcd = bid & 7;
    int chunk = bid >> 3;
    int row = xcd * 2000 + chunk * 4 + (int)(threadIdx.x >> 6);
    row = __builtin_amdgcn_readfirstlane(row);
    int lane = threadIdx.x & 63;
    int g = lane >> 4, s = lane & 15;
    int b = row / NN;

    const _Float16* yp = yhi + (size_t)row * DD + s * 8;
    H8 yh0, yh1;
    yh0.i4 = *(const int4*)yp;
    yh1.i4 = *(const int4*)(yp + 128);

    const _Float16* xph = xhi + (size_t)row * DD + s * 8;
    const _Float16* xpl = xlo + (size_t)row * DD + s * 8;
    H8 xih0, xih1, xil0, xil1;
    xih0.i4 = *(const int4*)xph;       xih1.i4 = *(const int4*)(xph + 128);
    xil0.i4 = *(const int4*)xpl;       xil1.i4 = *(const int4*)(xpl + 128);
    float xi[16];
    #pragma unroll
    for (int u = 0; u < 8; ++u) {
        xi[u]     = fmaf((float)xil0.h[u], INV_SPLIT, (float)xih0.h[u]);
        xi[8 + u] = fmaf((float)xil1.h[u], INV_SPLIT, (float)xih1.h[u]);
    }
    const _Float16* xb = xhi + (size_t)b * NN * DD;

    float p = 0.0f;
    #pragma unroll
    for (int u = 0; u < 8; ++u) {
        p = fmaf((float)yh0.h[u], xi[u], p);
        p = fmaf((float)yh1.h[u], xi[8 + u], p);
    }
    p += __shfl_xor(p, 1); p += __shfl_xor(p, 2);
    p += __shfl_xor(p, 4); p += __shfl_xor(p, 8);
    float wd = (g == 0) ? (__expf(p) + 1e-5f) * adiag[row] : 0.0f;
    float denom = wd;
    float acc[16];
    #pragma unroll
    for (int u = 0; u < 16; ++u) acc[u] = wd * xi[u];

    const int c = cnt[row];
    const int* ip = idx + (size_t)row * MAXNZ;
    const int iters = (c + 3) >> 2;

    int j0 = (g < c) ? ip[g] : 0;
    int j1 = (4 + g < c) ? ip[4 + g] : 0;
    bool vok = g < c;
    H8 v0, v1;
    {
        const _Float16* xp = xb + (size_t)j0 * DD + s * 8;
        v0.i4 = *(const int4*)xp;
        v1.i4 = *(const int4*)(xp + 128);
    }

    for (int t = 0; t < iters; ++t) {
        int k2 = (t + 2) * 4 + g;
        int j2 = (k2 < c) ? ip[k2] : 0;
        H8 n0, n1;
        const _Float16* np = xb + (size_t)j1 * DD + s * 8;
        n0.i4 = *(const int4*)np;
        n1.i4 = *(const int4*)(np + 128);

        float q = 0.0f;
        #pragma unroll
        for (int i = 0; i < 4; ++i) q = dot2f(yh0.p[i], v0.p[i], q);
        #pragma unroll
        for (int i = 0; i < 4; ++i) q = dot2f(yh1.p[i], v1.p[i], q);
        q += __shfl_xor(q, 1); q += __shfl_xor(q, 2);
        q += __shfl_xor(q, 4); q += __shfl_xor(q, 8);
        float w = vok ? __expf(q) : 0.0f;
        denom += w;
        #pragma unroll
        for (int u = 0; u < 8; ++u) {
            acc[u]     = fmaf(w, (float)v0.h[u], acc[u]);
            acc[8 + u] = fmaf(w, (float)v1.h[u], acc[8 + u]);
        }

        v0 = n0; v1 = n1;
        j1 = j2;
        vok = (t + 1) * 4 + g < c;
    }

#define XG(x) x += __shfl_xor(x, 16); x += __shfl_xor(x, 32);
    XG(denom);
    #pragma unroll
    for (int u = 0; u < 16; ++u) { XG(acc[u]) }
#undef XG

    float inv = 1.0f / denom;
    int half = (g & 1) * 8;
    H8 st;
    #pragma unroll
    for (int i = 0; i < 8; ++i) {
        float x = acc[half + i] * inv;
        _Float16 h = (_Float16)x;
        st.h[i] = (g & 2) ? (_Float16)((x - (float)h) * SPLIT_SCALE) : h;
    }
    _Float16* dst = ((g & 2) ? olo : ohi) + (size_t)row * DD + (g & 1) * 128 + s * 8;
    *(int4*)dst = st.i4;
}

// ---------------------------------------------------------------------------
// Kernel 3: split-fp16 MFMA GEMM v4.
// A (hi+lo) staged to LDS ONCE for all K (64KB, swizzled); B (weights,
// L2-resident) loaded global->reg in fragment layout; NO barriers in K-loop.
// BM=64, BN=128; 4 waves, wave tile 32x64 (2x4 of 16x16x32 MFMA).
// Epilogue: acc -> LDS fp32 transpose -> coalesced vectorized split stores.
// ---------------------------------------------------------------------------
__global__ __launch_bounds__(256, 2) void gemm16(
    const _Float16* __restrict__ Ahi, const _Float16* __restrict__ Alo,
    const _Float16* __restrict__ Bhi, const _Float16* __restrict__ Blo,
    const float* __restrict__ bias,
    const _Float16* __restrict__ Shi, const _Float16* __restrict__ Slo,
    _Float16* __restrict__ Chi, _Float16* __restrict__ Clo,
    float* __restrict__ Cf32, int relu)
{
    __shared__ __align__(16) char smem[65536];
    char* Ah = smem;             // [64 m][256 k] fp16 swizzled, 32 KB
    char* Al = smem + 32768;

    int tid = threadIdx.x;
    int mBase = blockIdx.y * 64;
    int nBase = blockIdx.x * 128;

    // ---- stage A once (whole K) ----
    {
        int r = tid & 63;                 // row 0..63 (lane-consecutive)
        int kc = (tid >> 6) * 64;         // k-chunk of 64 halves
        const _Float16* pAh = Ahi + (size_t)(mBase + r) * 256 + kc;
        const _Float16* pAl = Alo + (size_t)(mBase + r) * 256 + kc;
        int base = r * 512 + kc * 2;
        int swz = (r & 7) << 4;
        #pragma unroll
        for (int i = 0; i < 8; ++i) {
            *(int4*)(Ah + ((base + i * 16) ^ swz)) = *(const int4*)(pAh + i * 8);
            *(int4*)(Al + ((base + i * 16) ^ swz)) = *(const int4*)(pAl + i * 8);
        }
    }
    __syncthreads();

    int l = tid & 63, wv = tid >> 6;
    int wm = (wv & 1) * 32, wn = (wv >> 1) * 64;
    int lr = l & 15, lk = l >> 4;         // lk 0..3

    const _Float16* bh[4];
    const _Float16* bl[4];
    #pragma unroll
    for (int nt = 0; nt < 4; ++nt) {
        size_t ro = (size_t)(nBase + wn + nt * 16 + lr) * 256 + lk * 8;
        bh[nt] = Bhi + ro;
        bl[nt] = Blo + ro;
    }

    f32x4 acc0[2][4] = {};
    f32x4 acc1[2][4] = {};

    H8 nb[8];
    #pragma unroll
    for (int nt = 0; nt < 4; ++nt) {
        nb[nt].i4     = *(const int4*)(bh[nt]);
        nb[4 + nt].i4 = *(const int4*)(bl[nt]);
    }

    #pragma unroll
    for (int s = 0; s < 8; ++s) {
        H8 cb[8];
        #pragma unroll
        for (int i = 0; i < 8; ++i) cb[i] = nb[i];
        if (s < 7) {
            #pragma unroll
            for (int nt = 0; nt < 4; ++nt) {
                nb[nt].i4     = *(const int4*)(bh[nt] + (s + 1) * 32);
                nb[4 + nt].i4 = *(const int4*)(bl[nt] + (s + 1) * 32);
            }
        }
        f16x8 fah[2], fal[2];
        #pragma unroll
        for (int mt = 0; mt < 2; ++mt) {
            int ml = wm + mt * 16 + lr;
            int off = (ml * 512 + s * 64 + lk * 16) ^ ((ml & 7) << 4);
            fah[mt] = *(const f16x8*)(Ah + off);
            fal[mt] = *(const f16x8*)(Al + off);
        }
        #pragma unroll
        for (int mt = 0; mt < 2; ++mt)
            #pragma unroll
            for (int nt = 0; nt < 4; ++nt) {
                acc0[mt][nt] = __builtin_amdgcn_mfma_f32_16x16x32_f16(
                    fah[mt], cb[nt].v, acc0[mt][nt], 0, 0, 0);
                acc1[mt][nt] = __builtin_amdgcn_mfma_f32_16x16x32_f16(
                    fah[mt], cb[4 + nt].v, acc1[mt][nt], 0, 0, 0);
                acc1[mt][nt] = __builtin_amdgcn_mfma_f32_16x16x32_f16(
                    fal[mt], cb[nt].v, acc1[mt][nt], 0, 0, 0);
            }
    }

    // ---- epilogue: transpose through LDS, vectorized stores ----
    __syncthreads();
    float* T = (float*)smem;              // [64][132] fp32, 33.8 KB
    #pragma unroll
    for (int mt = 0; mt < 2; ++mt)
        #pragma unroll
        for (int nt = 0; nt < 4; ++nt)
            #pragma unroll
            for (int q = 0; q < 4; ++q) {
                int m = wm + mt * 16 + lk * 4 + q;
                int n = wn + nt * 16 + lr;
                T[m * 132 + n] = acc0[mt][nt][q] + acc1[mt][nt][q] * INV_SPLIT;
            }
    __syncthreads();

    {
        int r = tid >> 2;                 // out row 0..63
        int c0 = (tid & 3) * 32;          // 32 consecutive cols
        int m = mBase + r;
        int n0 = nBase + c0;
        float v[32];
        #pragma unroll
        for (int i = 0; i < 8; ++i) {
            float4 f = *(const float4*)&T[r * 132 + c0 + i * 4];
            v[i * 4 + 0] = f.x; v[i * 4 + 1] = f.y;
            v[i * 4 + 2] = f.z; v[i * 4 + 3] = f.w;
        }
        if (bias) {
            #pragma unroll
            for (int i = 0; i < 8; ++i) {
                float4 bv = *(const float4*)(bias + n0 + i * 4);
                v[i * 4 + 0] += bv.x; v[i * 4 + 1] += bv.y;
                v[i * 4 + 2] += bv.z; v[i * 4 + 3] += bv.w;
            }
        }
        if (relu) {
            #pragma unroll
            for (int i = 0; i < 32; ++i) v[i] = fmaxf(v[i], 0.0f);
        }
        size_t o = (size_t)m * 256 + n0;
        if (Shi) {
            #pragma unroll
            for (int j = 0; j < 4; ++j) {
                H8 sh, sl;
                sh.i4 = *(const int4*)(Shi + o + j * 8);
                sl.i4 = *(const int4*)(Slo + o + j * 8);
                #pragma unroll
                for (int u = 0; u < 8; ++u)
                    v[j * 8 + u] += fmaf((float)sl.h[u], INV_SPLIT, (float)sh.h[u]);
            }
        }
        if (Cf32) {
            #pragma unroll
            for (int i = 0; i < 8; ++i) {
                float4 f = make_float4(v[i * 4], v[i * 4 + 1], v[i * 4 + 2], v[i * 4 + 3]);
                *(float4*)(Cf32 + o + i * 4) = f;
            }
        } else {
            #pragma unroll
            for (int j = 0; j < 4; ++j) {
                H8 hh, ll;
                #pragma unroll
                for (int u = 0; u < 8; ++u) {
                    float x = v[j * 8 + u];
                    _Float16 h = (_Float16)x;
                    hh.h[u] = h;
                    ll.h[u] = (_Float16)((x - (float)h) * SPLIT_SCALE);
                }
                *(int4*)(Chi + o + j * 8) = hh.i4;
                *(int4*)(Clo + o + j * 8) = ll.i4;
            }
        }
    }
}

// ---------------------------------------------------------------------------
extern "C" void kernel_launch(void* const* d_in, const int* in_sizes, int n_in,
                              void* d_out, int out_size, void* d_ws, size_t ws_size,
                              hipStream_t stream)
{
    const float* x_in     = (const float*)d_in[0];
    const float* contacts = (const float*)d_in[1];
    const float* W_list   = (const float*)d_in[2];
    const float* dense_W  = (const float*)d_in[3];
    const float* dense_b  = (const float*)d_in[4];
    const float* final_W  = (const float*)d_in[5];
    const float* final_b  = (const float*)d_in[6];
    float* out = (float*)d_out;

    char* ws = (char*)d_ws;
    const size_t PL = (size_t)MROWS * DD;
    _Float16* pl[8];
    for (int i = 0; i < 8; ++i) pl[i] = (_Float16*)ws + (size_t)i * PL;
    char* p8 = ws + 8 * PL * sizeof(_Float16);
    int*   idx   = (int*)p8;
    int*   cnt   = (int*)(p8 + (size_t)MROWS * MAXNZ * sizeof(int));
    float* adiag = (float*)((char*)cnt + (size_t)MROWS * sizeof(int));
    _Float16* wt_hi = (_Float16*)((char*)adiag + (size_t)MROWS * sizeof(float));
    _Float16* wt_lo = wt_hi + (size_t)10 * 65536;

    convert_w<<<160, 256, 0, stream>>>(W_list, dense_W, final_W, wt_hi, wt_lo);
    convert_x<<<MROWS * DD / (256 * 8), 256, 0, stream>>>(x_in, pl[0], pl[1]);
    build_sparse<<<MROWS / 4, 256, 0, stream>>>(contacts, idx, cnt, adiag);

    dim3 gg(2, MROWS / 64);   // (2, 250)
    int cur = 0;
    for (int l = 0; l < LL; ++l) {
        int oth = 1 - cur;
        _Float16 *x0h = pl[2 * cur], *x0l = pl[2 * cur + 1];
        _Float16 *yh  = pl[2 * oth], *yl  = pl[2 * oth + 1];
        _Float16 *xah = pl[4], *xal = pl[5];
        _Float16 *xbh = pl[6], *xbl = pl[7];
        // y = x0 @ W_l
        gemm16<<<gg, 256, 0, stream>>>(x0h, x0l,
                                       wt_hi + (size_t)l * 65536,
                                       wt_lo + (size_t)l * 65536,
                                       nullptr, nullptr, nullptr,
                                       yh, yl, nullptr, 0);
        // sparse attention aggregate
        sparse_agg<<<MROWS / 4, 256, 0, stream>>>(yh, x0h, x0l, idx, cnt, adiag,
                                                  xah, xal);
        // dense 1 (relu)
        gemm16<<<gg, 256, 0, stream>>>(xah, xal,
                                       wt_hi + (size_t)(3 + l * 2) * 65536,
                                       wt_lo + (size_t)(3 + l * 2) * 65536,
                                       dense_b + (size_t)(l * 2 + 0) * 256,
                                       nullptr, nullptr,
                                       xbh, xbl, nullptr, 1);
        // dense 2 (relu) + skip(x0) -> next X0
        gemm16<<<gg, 256, 0, stream>>>(xbh, xbl,
                                       wt_hi + (size_t)(4 + l * 2) * 65536,
                                       wt_lo + (size_t)(4 + l * 2) * 65536,
                                       dense_b + (size_t)(l * 2 + 1) * 256,
                                       x0h, x0l,
                                       yh, yl, nullptr, 1);
        cur = oth;
    }
    // final projection -> fp32 d_out
    gemm16<<<gg, 256, 0, stream>>>(pl[2 * cur], pl[2 * cur + 1],
                                   wt_hi + (size_t)9 * 65536,
                                   wt_lo + (size_t)9 * 65536,
                                   final_b, nullptr, nullptr,
                                   nullptr, nullptr, out, 0);
}

// Round 9
// 308.927 us; speedup vs baseline: 1.3303x; 1.3303x over previous
//
#include <hip/hip_runtime.h>

#define BB 16
#define NN 1000
#define DD 256
#define LL 3
#define MAXNZ 256
#define MROWS (BB * NN)
#define SPLIT_SCALE 2048.0f
#define INV_SPLIT 4.8828125e-4f

typedef _Float16 f16x8 __attribute__((ext_vector_type(8)));
typedef _Float16 f16x2 __attribute__((ext_vector_type(2)));
typedef float f32x4 __attribute__((ext_vector_type(4)));

union H8 { f16x8 v; f16x2 p[4]; _Float16 h[8]; int4 i4; };

#if defined(__has_builtin)
#if __has_builtin(__builtin_amdgcn_fdot2)
#define HAS_FDOT2 1
#endif
#endif

__device__ __forceinline__ float dot2f(f16x2 a, f16x2 b, float c) {
#ifdef HAS_FDOT2
    return __builtin_amdgcn_fdot2(a, b, c, false);
#else
    return fmaf((float)a[0], (float)b[0], fmaf((float)a[1], (float)b[1], c));
#endif
}

// ---------------------------------------------------------------------------
// Kernel 0a: split+transpose the 10 weight matrices -> wt[mat][n][k] hi/lo.
// ---------------------------------------------------------------------------
__global__ __launch_bounds__(256) void convert_w(
    const float* __restrict__ W_list, const float* __restrict__ dense_W,
    const float* __restrict__ final_W,
    _Float16* __restrict__ wt_hi, _Float16* __restrict__ wt_lo)
{
    __shared__ float T[64][68];
    int blk = blockIdx.x;          // 10 mats * 16 tiles
    int mat = blk >> 4;
    int tile = blk & 15;
    int tk = (tile >> 2) * 64, tn = (tile & 3) * 64;
    const float* src = (mat < 3) ? (W_list + (size_t)mat * 65536)
                     : (mat < 9) ? (dense_W + (size_t)(mat - 3) * 65536)
                                 : final_W;
    int t = threadIdx.x;
    {
        int k = t >> 2, nc = (t & 3) * 16;
        const float* sp = src + (size_t)(tk + k) * 256 + tn + nc;
        *(float4*)&T[k][nc + 0]  = *(const float4*)(sp + 0);
        *(float4*)&T[k][nc + 4]  = *(const float4*)(sp + 4);
        *(float4*)&T[k][nc + 8]  = *(const float4*)(sp + 8);
        *(float4*)&T[k][nc + 12] = *(const float4*)(sp + 12);
    }
    __syncthreads();
    int n = t >> 2, kc = (t & 3) * 16;
    H8 hh0, hh1, ll0, ll1;
    #pragma unroll
    for (int i = 0; i < 16; ++i) {
        float x = T[kc + i][n];
        _Float16 hi = (_Float16)x;
        _Float16 lo = (_Float16)((x - (float)hi) * SPLIT_SCALE);
        if (i < 8) { hh0.h[i] = hi; ll0.h[i] = lo; }
        else       { hh1.h[i - 8] = hi; ll1.h[i - 8] = lo; }
    }
    size_t o = (size_t)mat * 65536 + (size_t)(tn + n) * 256 + tk + kc;
    *(int4*)(wt_hi + o)     = hh0.i4;
    *(int4*)(wt_hi + o + 8) = hh1.i4;
    *(int4*)(wt_lo + o)     = ll0.i4;
    *(int4*)(wt_lo + o + 8) = ll1.i4;
}

// ---------------------------------------------------------------------------
// Kernel 0b: split x_in fp32 -> hi/lo fp16 planes.
// ---------------------------------------------------------------------------
__global__ __launch_bounds__(256) void convert_x(
    const float* __restrict__ in, _Float16* __restrict__ hi,
    _Float16* __restrict__ lo)
{
    size_t gid = (size_t)blockIdx.x * 256 + threadIdx.x;
    const float* p = in + gid * 8;
    float4 a = *(const float4*)p;
    float4 b = *(const float4*)(p + 4);
    float xs[8] = {a.x, a.y, a.z, a.w, b.x, b.y, b.z, b.w};
    H8 hh, ll;
    #pragma unroll
    for (int i = 0; i < 8; ++i) {
        _Float16 h = (_Float16)xs[i];
        hh.h[i] = h;
        ll.h[i] = (_Float16)((xs[i] - (float)h) * SPLIT_SCALE);
    }
    *(int4*)(hi + gid * 8) = hh.i4;
    *(int4*)(lo + gid * 8) = ll.i4;
}

// ---------------------------------------------------------------------------
// Kernel 1: build sparse structure of A = prot_contacts + eye.
// ---------------------------------------------------------------------------
__global__ __launch_bounds__(256) void build_sparse(
    const float* __restrict__ contacts,
    int* __restrict__ idx, int* __restrict__ cnt, float* __restrict__ adiag)
{
    int wave = (int)((blockIdx.x * blockDim.x + threadIdx.x) >> 6);
    int lane = threadIdx.x & 63;
    if (wave >= MROWS) return;
    int b = wave / NN;
    int i = wave - b * NN;
    const float* row = contacts + (size_t)b * NN * NN + (size_t)i * NN;
    int* out = idx + (size_t)wave * MAXNZ;
    int count = 0;
    for (int j0 = 0; j0 < NN; j0 += 64) {
        int j = j0 + lane;
        float v = (j < NN) ? row[j] : 0.0f;
        bool p = (v != 0.0f) && (j != i);
        unsigned long long bal = __ballot(p);
        if (p) {
            int pre = __popcll(bal & ((1ull << lane) - 1ull));
            out[count + pre] = j;
        }
        count += __popcll(bal);
    }
    if (lane == 0) {
        cnt[wave] = count;
        adiag[wave] = row[i] + 1.0f;
    }
}

// ---------------------------------------------------------------------------
// Kernel 2: sparse attention aggregate v4 (round-6, known-good).
// 1 wave per row; 16-lane group holds full 256-dim row (8+8 halves/lane).
// 4 neighbors in flight; 2-deep index + 1-deep data pipeline. XCD-local rows.
// ---------------------------------------------------------------------------
__global__ __launch_bounds__(256) void sparse_agg(
    const _Float16* __restrict__ yhi,
    const _Float16* __restrict__ xhi, const _Float16* __restrict__ xlo,
    const int* __restrict__ idx, const int* __restrict__ cnt,
    const float* __restrict__ adiag,
    _Float16* __restrict__ ohi, _Float16* __restrict__ olo)
{
    int bid = blockIdx.x;
    int xcd = bid & 7;
    int chunk = bid >> 3;
    int row = xcd * 2000 + chunk * 4 + (int)(threadIdx.x >> 6);
    row = __builtin_amdgcn_readfirstlane(row);
    int lane = threadIdx.x & 63;
    int g = lane >> 4, s = lane & 15;
    int b = row / NN;

    const _Float16* yp = yhi + (size_t)row * DD + s * 8;
    H8 yh0, yh1;
    yh0.i4 = *(const int4*)yp;
    yh1.i4 = *(const int4*)(yp + 128);

    const _Float16* xph = xhi + (size_t)row * DD + s * 8;
    const _Float16* xpl = xlo + (size_t)row * DD + s * 8;
    H8 xih0, xih1, xil0, xil1;
    xih0.i4 = *(const int4*)xph;       xih1.i4 = *(const int4*)(xph + 128);
    xil0.i4 = *(const int4*)xpl;       xil1.i4 = *(const int4*)(xpl + 128);
    float xi[16];
    #pragma unroll
    for (int u = 0; u < 8; ++u) {
        xi[u]     = fmaf((float)xil0.h[u], INV_SPLIT, (float)xih0.h[u]);
        xi[8 + u] = fmaf((float)xil1.h[u], INV_SPLIT, (float)xih1.h[u]);
    }
    const _Float16* xb = xhi + (size_t)b * NN * DD;

    float p = 0.0f;
    #pragma unroll
    for (int u = 0; u < 8; ++u) {
        p = fmaf((float)yh0.h[u], xi[u], p);
        p = fmaf((float)yh1.h[u], xi[8 + u], p);
    }
    p += __shfl_xor(p, 1); p += __shfl_xor(p, 2);
    p += __shfl_xor(p, 4); p += __shfl_xor(p, 8);
    float wd = (g == 0) ? (__expf(p) + 1e-5f) * adiag[row] : 0.0f;
    float denom = wd;
    float acc[16];
    #pragma unroll
    for (int u = 0; u < 16; ++u) acc[u] = wd * xi[u];

    const int c = cnt[row];
    const int* ip = idx + (size_t)row * MAXNZ;
    const int iters = (c + 3) >> 2;

    int j0 = (g < c) ? ip[g] : 0;
    int j1 = (4 + g < c) ? ip[4 + g] : 0;
    bool vok = g < c;
    H8 v0, v1;
    {
        const _Float16* xp = xb + (size_t)j0 * DD + s * 8;
        v0.i4 = *(const int4*)xp;
        v1.i4 = *(const int4*)(xp + 128);
    }

    for (int t = 0; t < iters; ++t) {
        int k2 = (t + 2) * 4 + g;
        int j2 = (k2 < c) ? ip[k2] : 0;
        H8 n0, n1;
        const _Float16* np = xb + (size_t)j1 * DD + s * 8;
        n0.i4 = *(const int4*)np;
        n1.i4 = *(const int4*)(np + 128);

        float q = 0.0f;
        #pragma unroll
        for (int i = 0; i < 4; ++i) q = dot2f(yh0.p[i], v0.p[i], q);
        #pragma unroll
        for (int i = 0; i < 4; ++i) q = dot2f(yh1.p[i], v1.p[i], q);
        q += __shfl_xor(q, 1); q += __shfl_xor(q, 2);
        q += __shfl_xor(q, 4); q += __shfl_xor(q, 8);
        float w = vok ? __expf(q) : 0.0f;
        denom += w;
        #pragma unroll
        for (int u = 0; u < 8; ++u) {
            acc[u]     = fmaf(w, (float)v0.h[u], acc[u]);
            acc[8 + u] = fmaf(w, (float)v1.h[u], acc[8 + u]);
        }

        v0 = n0; v1 = n1;
        j1 = j2;
        vok = (t + 1) * 4 + g < c;
    }

#define XG(x) x += __shfl_xor(x, 16); x += __shfl_xor(x, 32);
    XG(denom);
    #pragma unroll
    for (int u = 0; u < 16; ++u) { XG(acc[u]) }
#undef XG

    float inv = 1.0f / denom;
    int half = (g & 1) * 8;
    H8 st;
    #pragma unroll
    for (int i = 0; i < 8; ++i) {
        float x = acc[half + i] * inv;
        _Float16 h = (_Float16)x;
        st.h[i] = (g & 2) ? (_Float16)((x - (float)h) * SPLIT_SCALE) : h;
    }
    _Float16* dst = ((g & 2) ? olo : ohi) + (size_t)row * DD + (g & 1) * 128 + s * 8;
    *(int4*)dst = st.i4;
}

// ---------------------------------------------------------------------------
// Kernel 3: split-fp16 MFMA GEMM v5 — occupancy-first.
// BM=BN=64, BK=64; 4 waves, wave tile 32x32 (2x2 of 16x16x32 MFMA).
// LDS 32KB (5 blocks/CU), __launch_bounds__(256,4) (~110 VGPR -> 4 waves/SIMD).
// Grid (4,250)=1000 blocks ~= 4 co-resident blocks/CU: TLP hides staging
// latency instead of software pipelining.
// ---------------------------------------------------------------------------
__global__ __launch_bounds__(256, 4) void gemm16(
    const _Float16* __restrict__ Ahi, const _Float16* __restrict__ Alo,
    const _Float16* __restrict__ Bhi, const _Float16* __restrict__ Blo,
    const float* __restrict__ bias,
    const _Float16* __restrict__ Shi, const _Float16* __restrict__ Slo,
    _Float16* __restrict__ Chi, _Float16* __restrict__ Clo,
    float* __restrict__ Cf32, int relu)
{
    __shared__ __align__(16) char smem[32768];
    char* Ah = smem;             // [64 m][64 k] halves, swizzled, 8 KB each
    char* Al = smem + 8192;
    char* Bh = smem + 16384;
    char* Bl = smem + 24576;

    int tid = threadIdx.x;
    int mBase = blockIdx.y * 64;
    int nBase = blockIdx.x * 64;

    int r = tid >> 2;                // staging row 0..63
    int kc = (tid & 3) * 16;         // k offset in halves
    const _Float16* gAh = Ahi + (size_t)(mBase + r) * 256 + kc;
    const _Float16* gAl = Alo + (size_t)(mBase + r) * 256 + kc;
    const _Float16* gBh = Bhi + (size_t)(nBase + r) * 256 + kc;
    const _Float16* gBl = Blo + (size_t)(nBase + r) * 256 + kc;
    int sbase = r * 128 + kc * 2;
    int swz = (r & 7) << 4;

    int l = tid & 63, wv = tid >> 6;
    int wm = (wv & 1) * 32, wn = (wv >> 1) * 32;
    int lr = l & 15, lk = l >> 4;

    f32x4 acc0[2][2] = {};
    f32x4 acc1[2][2] = {};

    for (int kb = 0; kb < 256; kb += 64) {
        int4 a0 = *(const int4*)(gAh + kb);
        int4 a1 = *(const int4*)(gAh + kb + 8);
        int4 a2 = *(const int4*)(gAl + kb);
        int4 a3 = *(const int4*)(gAl + kb + 8);
        int4 b0 = *(const int4*)(gBh + kb);
        int4 b1 = *(const int4*)(gBh + kb + 8);
        int4 b2 = *(const int4*)(gBl + kb);
        int4 b3 = *(const int4*)(gBl + kb + 8);
        __syncthreads();
        *(int4*)(Ah + ((sbase +  0) ^ swz)) = a0;
        *(int4*)(Ah + ((sbase + 16) ^ swz)) = a1;
        *(int4*)(Al + ((sbase +  0) ^ swz)) = a2;
        *(int4*)(Al + ((sbase + 16) ^ swz)) = a3;
        *(int4*)(Bh + ((sbase +  0) ^ swz)) = b0;
        *(int4*)(Bh + ((sbase + 16) ^ swz)) = b1;
        *(int4*)(Bl + ((sbase +  0) ^ swz)) = b2;
        *(int4*)(Bl + ((sbase + 16) ^ swz)) = b3;
        __syncthreads();

        #pragma unroll
        for (int kk = 0; kk < 2; ++kk) {
            int kby = kk * 64 + lk * 16;
            f16x8 fah[2], fal[2], fbh[2], fbl[2];
            #pragma unroll
            for (int mt = 0; mt < 2; ++mt) {
                int ml = wm + mt * 16 + lr;
                int off = (ml * 128 + kby) ^ ((ml & 7) << 4);
                fah[mt] = *(const f16x8*)(Ah + off);
                fal[mt] = *(const f16x8*)(Al + off);
            }
            #pragma unroll
            for (int nt = 0; nt < 2; ++nt) {
                int nl = wn + nt * 16 + lr;
                int off = (nl * 128 + kby) ^ ((nl & 7) << 4);
                fbh[nt] = *(const f16x8*)(Bh + off);
                fbl[nt] = *(const f16x8*)(Bl + off);
            }
            #pragma unroll
            for (int mt = 0; mt < 2; ++mt)
                #pragma unroll
                for (int nt = 0; nt < 2; ++nt) {
                    acc0[mt][nt] = __builtin_amdgcn_mfma_f32_16x16x32_f16(
                        fah[mt], fbh[nt], acc0[mt][nt], 0, 0, 0);
                    acc1[mt][nt] = __builtin_amdgcn_mfma_f32_16x16x32_f16(
                        fah[mt], fbl[nt], acc1[mt][nt], 0, 0, 0);
                    acc1[mt][nt] = __builtin_amdgcn_mfma_f32_16x16x32_f16(
                        fal[mt], fbh[nt], acc1[mt][nt], 0, 0, 0);
                }
        }
    }

    // epilogue: C/D layout col = lane&15, row = (lane>>4)*4 + q
    #pragma unroll
    for (int mt = 0; mt < 2; ++mt) {
        #pragma unroll
        for (int nt = 0; nt < 2; ++nt) {
            int n = nBase + wn + nt * 16 + lr;
            float bv = bias ? bias[n] : 0.0f;
            #pragma unroll
            for (int q = 0; q < 4; ++q) {
                int m = mBase + wm + mt * 16 + lk * 4 + q;
                size_t o = (size_t)m * 256 + n;
                float v = acc0[mt][nt][q] + acc1[mt][nt][q] * INV_SPLIT + bv;
                if (relu) v = fmaxf(v, 0.0f);
                if (Shi) v += (float)Shi[o] + (float)Slo[o] * INV_SPLIT;
                if (Cf32) {
                    Cf32[o] = v;
                } else {
                    _Float16 hh = (_Float16)v;
                    Chi[o] = hh;
                    Clo[o] = (_Float16)((v - (float)hh) * SPLIT_SCALE);
                }
            }
        }
    }
}

// ---------------------------------------------------------------------------
extern "C" void kernel_launch(void* const* d_in, const int* in_sizes, int n_in,
                              void* d_out, int out_size, void* d_ws, size_t ws_size,
                              hipStream_t stream)
{
    const float* x_in     = (const float*)d_in[0];
    const float* contacts = (const float*)d_in[1];
    const float* W_list   = (const float*)d_in[2];
    const float* dense_W  = (const float*)d_in[3];
    const float* dense_b  = (const float*)d_in[4];
    const float* final_W  = (const float*)d_in[5];
    const float* final_b  = (const float*)d_in[6];
    float* out = (float*)d_out;

    char* ws = (char*)d_ws;
    const size_t PL = (size_t)MROWS * DD;
    _Float16* pl[8];
    for (int i = 0; i < 8; ++i) pl[i] = (_Float16*)ws + (size_t)i * PL;
    char* p8 = ws + 8 * PL * sizeof(_Float16);
    int*   idx   = (int*)p8;
    int*   cnt   = (int*)(p8 + (size_t)MROWS * MAXNZ * sizeof(int));
    float* adiag = (float*)((char*)cnt + (size_t)MROWS * sizeof(int));
    _Float16* wt_hi = (_Float16*)((char*)adiag + (size_t)MROWS * sizeof(float));
    _Float16* wt_lo = wt_hi + (size_t)10 * 65536;

    convert_w<<<160, 256, 0, stream>>>(W_list, dense_W, final_W, wt_hi, wt_lo);
    convert_x<<<MROWS * DD / (256 * 8), 256, 0, stream>>>(x_in, pl[0], pl[1]);
    build_sparse<<<MROWS / 4, 256, 0, stream>>>(contacts, idx, cnt, adiag);

    dim3 gg(4, MROWS / 64);   // (4, 250) = 1000 blocks
    int cur = 0;
    for (int l = 0; l < LL; ++l) {
        int oth = 1 - cur;
        _Float16 *x0h = pl[2 * cur], *x0l = pl[2 * cur + 1];
        _Float16 *yh  = pl[2 * oth], *yl  = pl[2 * oth + 1];
        _Float16 *xah = pl[4], *xal = pl[5];
        _Float16 *xbh = pl[6], *xbl = pl[7];
        // y = x0 @ W_l
        gemm16<<<gg, 256, 0, stream>>>(x0h, x0l,
                                       wt_hi + (size_t)l * 65536,
                                       wt_lo + (size_t)l * 65536,
                                       nullptr, nullptr, nullptr,
                                       yh, yl, nullptr, 0);
        // sparse attention aggregate
        sparse_agg<<<MROWS / 4, 256, 0, stream>>>(yh, x0h, x0l, idx, cnt, adiag,
                                                  xah, xal);
        // dense 1 (relu)
        gemm16<<<gg, 256, 0, stream>>>(xah, xal,
                                       wt_hi + (size_t)(3 + l * 2) * 65536,
                                       wt_lo + (size_t)(3 + l * 2) * 65536,
                                       dense_b + (size_t)(l * 2 + 0) * 256,
                                       nullptr, nullptr,
                                       xbh, xbl, nullptr, 1);
        // dense 2 (relu) + skip(x0) -> next X0
        gemm16<<<gg, 256, 0, stream>>>(xbh, xbl,
                                       wt_hi + (size_t)(4 + l * 2) * 65536,
                                       wt_lo + (size_t)(4 + l * 2) * 65536,
                                       dense_b + (size_t)(l * 2 + 1) * 256,
                                       x0h, x0l,
                                       yh, yl, nullptr, 1);
        cur = oth;
    }
    // final projection -> fp32 d_out
    gemm16<<<gg, 256, 0, stream>>>(pl[2 * cur], pl[2 * cur + 1],
                                   wt_hi + (size_t)9 * 65536,
                                   wt_lo + (size_t)9 * 65536,
                                   final_b, nullptr, nullptr,
                                   nullptr, nullptr, out, 0);
}

// Round 10
// 303.029 us; speedup vs baseline: 1.3562x; 1.0195x over previous
//
#include <hip/hip_runtime.h>

#define BB 16
#define NN 1000
#define DD 256
#define LL 3
#define MAXNZ 256
#define MROWS (BB * NN)
#define SPLIT_SCALE 2048.0f
#define INV_SPLIT 4.8828125e-4f

typedef _Float16 f16x8 __attribute__((ext_vector_type(8)));
typedef _Float16 f16x2 __attribute__((ext_vector_type(2)));
typedef float f32x4 __attribute__((ext_vector_type(4)));

union H8 { f16x8 v; f16x2 p[4]; _Float16 h[8]; int4 i4; };

#if defined(__has_builtin)
#if __has_builtin(__builtin_amdgcn_fdot2)
#define HAS_FDOT2 1
#endif
#endif

__device__ __forceinline__ float dot2f(f16x2 a, f16x2 b, float c) {
#ifdef HAS_FDOT2
    return __builtin_amdgcn_fdot2(a, b, c, false);
#else
    return fmaf((float)a[0], (float)b[0], fmaf((float)a[1], (float)b[1], c));
#endif
}

// ---------------------------------------------------------------------------
// Kernel 0 (fused setup): blocks [0,160) convert_w, [160,2160) convert_x,
// [2160,6160) build_sparse. All independent; fusing removes 2 launch gaps
// and overlaps HBM-bound contact scan with VALU-bound converts.
// ---------------------------------------------------------------------------
__global__ __launch_bounds__(256) void setup_all(
    const float* __restrict__ W_list, const float* __restrict__ dense_W,
    const float* __restrict__ final_W,
    _Float16* __restrict__ wt_hi, _Float16* __restrict__ wt_lo,
    const float* __restrict__ x_in,
    _Float16* __restrict__ xh, _Float16* __restrict__ xl,
    const float* __restrict__ contacts,
    int* __restrict__ idx, int* __restrict__ cnt, float* __restrict__ adiag)
{
    __shared__ float T[64][68];
    int bid = blockIdx.x;
    int t = threadIdx.x;

    if (bid < 160) {
        // ---- convert_w: split+transpose weights -> [mat][n][k] hi/lo ----
        int mat = bid >> 4;
        int tile = bid & 15;
        int tk = (tile >> 2) * 64, tn = (tile & 3) * 64;
        const float* src = (mat < 3) ? (W_list + (size_t)mat * 65536)
                         : (mat < 9) ? (dense_W + (size_t)(mat - 3) * 65536)
                                     : final_W;
        {
            int k = t >> 2, nc = (t & 3) * 16;
            const float* sp = src + (size_t)(tk + k) * 256 + tn + nc;
            *(float4*)&T[k][nc + 0]  = *(const float4*)(sp + 0);
            *(float4*)&T[k][nc + 4]  = *(const float4*)(sp + 4);
            *(float4*)&T[k][nc + 8]  = *(const float4*)(sp + 8);
            *(float4*)&T[k][nc + 12] = *(const float4*)(sp + 12);
        }
        __syncthreads();
        int n = t >> 2, kc = (t & 3) * 16;
        H8 hh0, hh1, ll0, ll1;
        #pragma unroll
        for (int i = 0; i < 16; ++i) {
            float x = T[kc + i][n];
            _Float16 hi = (_Float16)x;
            _Float16 lo = (_Float16)((x - (float)hi) * SPLIT_SCALE);
            if (i < 8) { hh0.h[i] = hi; ll0.h[i] = lo; }
            else       { hh1.h[i - 8] = hi; ll1.h[i - 8] = lo; }
        }
        size_t o = (size_t)mat * 65536 + (size_t)(tn + n) * 256 + tk + kc;
        *(int4*)(wt_hi + o)     = hh0.i4;
        *(int4*)(wt_hi + o + 8) = hh1.i4;
        *(int4*)(wt_lo + o)     = ll0.i4;
        *(int4*)(wt_lo + o + 8) = ll1.i4;
    } else if (bid < 2160) {
        // ---- convert_x: fp32 -> hi/lo fp16 planes ----
        size_t gid = (size_t)(bid - 160) * 256 + t;
        const float* p = x_in + gid * 8;
        float4 a = *(const float4*)p;
        float4 b = *(const float4*)(p + 4);
        float xs[8] = {a.x, a.y, a.z, a.w, b.x, b.y, b.z, b.w};
        H8 hh, ll;
        #pragma unroll
        for (int i = 0; i < 8; ++i) {
            _Float16 h = (_Float16)xs[i];
            hh.h[i] = h;
            ll.h[i] = (_Float16)((xs[i] - (float)h) * SPLIT_SCALE);
        }
        *(int4*)(xh + gid * 8) = hh.i4;
        *(int4*)(xl + gid * 8) = ll.i4;
    } else {
        // ---- build_sparse: CSR structure of A = contacts + eye ----
        int wave = (int)(((size_t)(bid - 2160) * 256 + t) >> 6);
        int lane = t & 63;
        int b = wave / NN;
        int i = wave - b * NN;
        const float* row = contacts + (size_t)b * NN * NN + (size_t)i * NN;
        int* out = idx + (size_t)wave * MAXNZ;
        int count = 0;
        for (int j0 = 0; j0 < NN; j0 += 64) {
            int j = j0 + lane;
            float v = (j < NN) ? row[j] : 0.0f;
            bool p = (v != 0.0f) && (j != i);
            unsigned long long bal = __ballot(p);
            if (p) {
                int pre = __popcll(bal & ((1ull << lane) - 1ull));
                out[count + pre] = j;
            }
            count += __popcll(bal);
        }
        if (lane == 0) {
            cnt[wave] = count;
            adiag[wave] = row[i] + 1.0f;
        }
    }
}

// ---------------------------------------------------------------------------
// Kernel 2: sparse attention aggregate v6 — depth-2 data pipeline.
// 1 wave per row; 16-lane group holds full 256-dim row (8+8 halves/lane).
// 4 neighbors in flight per body; data for t+1 AND t+2 in flight -> ~2 bodies
// (~200cy) between load issue and use, covering L2/L3 gather latency.
// XCD-local row chunks (per-XCD gather set 2MB < 4MB L2).
// ---------------------------------------------------------------------------
__global__ __launch_bounds__(256) void sparse_agg(
    const _Float16* __restrict__ yhi,
    const _Float16* __restrict__ xhi, const _Float16* __restrict__ xlo,
    const int* __restrict__ idx, const int* __restrict__ cnt,
    const float* __restrict__ adiag,
    _Float16* __restrict__ ohi, _Float16* __restrict__ olo)
{
    int bid = blockIdx.x;
    int xcd = bid & 7;
    int chunk = bid >> 3;
    int row = xcd * 2000 + chunk * 4 + (int)(threadIdx.x >> 6);
    row = __builtin_amdgcn_readfirstlane(row);
    int lane = threadIdx.x & 63;
    int g = lane >> 4, s = lane & 15;
    int b = row / NN;

    const _Float16* yp = yhi + (size_t)row * DD + s * 8;
    H8 yh0, yh1;
    yh0.i4 = *(const int4*)yp;
    yh1.i4 = *(const int4*)(yp + 128);

    const _Float16* xph = xhi + (size_t)row * DD + s * 8;
    const _Float16* xpl = xlo + (size_t)row * DD + s * 8;
    H8 xih0, xih1, xil0, xil1;
    xih0.i4 = *(const int4*)xph;       xih1.i4 = *(const int4*)(xph + 128);
    xil0.i4 = *(const int4*)xpl;       xil1.i4 = *(const int4*)(xpl + 128);
    float xi[16];
    #pragma unroll
    for (int u = 0; u < 8; ++u) {
        xi[u]     = fmaf((float)xil0.h[u], INV_SPLIT, (float)xih0.h[u]);
        xi[8 + u] = fmaf((float)xil1.h[u], INV_SPLIT, (float)xih1.h[u]);
    }
    const _Float16* xb = xhi + (size_t)b * NN * DD;

    float p = 0.0f;
    #pragma unroll
    for (int u = 0; u < 8; ++u) {
        p = fmaf((float)yh0.h[u], xi[u], p);
        p = fmaf((float)yh1.h[u], xi[8 + u], p);
    }
    p += __shfl_xor(p, 1); p += __shfl_xor(p, 2);
    p += __shfl_xor(p, 4); p += __shfl_xor(p, 8);
    float wd = (g == 0) ? (__expf(p) + 1e-5f) * adiag[row] : 0.0f;
    float denom = wd;
    float acc[16];
    #pragma unroll
    for (int u = 0; u < 16; ++u) acc[u] = wd * xi[u];

    const int c = cnt[row];
    const int* ip = idx + (size_t)row * MAXNZ;
    const int iters = (c + 3) >> 2;

    // depth-2 pipeline prologue: data for t=0 (v) and t=1 (n); idx for t=2.
    int j2;
    H8 v0, v1, n0, n1;
    {
        int ja = (g < c) ? ip[g] : 0;
        int jb = (4 + g < c) ? ip[4 + g] : 0;
        j2 = (8 + g < c) ? ip[8 + g] : 0;
        const _Float16* p0 = xb + (size_t)ja * DD + s * 8;
        v0.i4 = *(const int4*)p0;
        v1.i4 = *(const int4*)(p0 + 128);
        const _Float16* p1 = xb + (size_t)jb * DD + s * 8;
        n0.i4 = *(const int4*)p1;
        n1.i4 = *(const int4*)(p1 + 128);
    }

    for (int t = 0; t < iters; ++t) {
        // issue: idx for t+3, data for t+2
        int k3 = (t + 3) * 4 + g;
        int j3 = (k3 < c) ? ip[k3] : 0;
        H8 m0, m1;
        const _Float16* mp = xb + (size_t)j2 * DD + s * 8;
        m0.i4 = *(const int4*)mp;
        m1.i4 = *(const int4*)(mp + 128);

        bool vok = t * 4 + g < c;
        float q = 0.0f;
        #pragma unroll
        for (int i = 0; i < 4; ++i) q = dot2f(yh0.p[i], v0.p[i], q);
        #pragma unroll
        for (int i = 0; i < 4; ++i) q = dot2f(yh1.p[i], v1.p[i], q);
        q += __shfl_xor(q, 1); q += __shfl_xor(q, 2);
        q += __shfl_xor(q, 4); q += __shfl_xor(q, 8);
        float w = vok ? __expf(q) : 0.0f;
        denom += w;
        #pragma unroll
        for (int u = 0; u < 8; ++u) {
            acc[u]     = fmaf(w, (float)v0.h[u], acc[u]);
            acc[8 + u] = fmaf(w, (float)v1.h[u], acc[8 + u]);
        }

        v0 = n0; v1 = n1;
        n0 = m0; n1 = m1;
        j2 = j3;
    }

#define XG(x) x += __shfl_xor(x, 16); x += __shfl_xor(x, 32);
    XG(denom);
    #pragma unroll
    for (int u = 0; u < 16; ++u) { XG(acc[u]) }
#undef XG

    float inv = 1.0f / denom;
    int half = (g & 1) * 8;
    H8 st;
    #pragma unroll
    for (int i = 0; i < 8; ++i) {
        float x = acc[half + i] * inv;
        _Float16 h = (_Float16)x;
        st.h[i] = (g & 2) ? (_Float16)((x - (float)h) * SPLIT_SCALE) : h;
    }
    _Float16* dst = ((g & 2) ? olo : ohi) + (size_t)row * DD + (g & 1) * 128 + s * 8;
    *(int4*)dst = st.i4;
}

// ---------------------------------------------------------------------------
// Kernel 3: split-fp16 MFMA GEMM v6 — v5 geometry + register prefetch.
// BM=BN=64, BK=64; 4 waves, wave tile 32x32 (2x2 of 16x16x32 MFMA).
// LDS 32KB; __launch_bounds__(256,3). Loads for chunk kb+1 issued right
// after the staging barrier so L2 latency hides under compute(kb).
// ---------------------------------------------------------------------------
__global__ __launch_bounds__(256, 3) void gemm16(
    const _Float16* __restrict__ Ahi, const _Float16* __restrict__ Alo,
    const _Float16* __restrict__ Bhi, const _Float16* __restrict__ Blo,
    const float* __restrict__ bias,
    const _Float16* __restrict__ Shi, const _Float16* __restrict__ Slo,
    _Float16* __restrict__ Chi, _Float16* __restrict__ Clo,
    float* __restrict__ Cf32, int relu)
{
    __shared__ __align__(16) char smem[32768];
    char* Ah = smem;
    char* Al = smem + 8192;
    char* Bh = smem + 16384;
    char* Bl = smem + 24576;

    int tid = threadIdx.x;
    int mBase = blockIdx.y * 64;
    int nBase = blockIdx.x * 64;

    int r = tid >> 2;
    int kc = (tid & 3) * 16;
    const _Float16* gAh = Ahi + (size_t)(mBase + r) * 256 + kc;
    const _Float16* gAl = Alo + (size_t)(mBase + r) * 256 + kc;
    const _Float16* gBh = Bhi + (size_t)(nBase + r) * 256 + kc;
    const _Float16* gBl = Blo + (size_t)(nBase + r) * 256 + kc;
    int sbase = r * 128 + kc * 2;
    int swz = (r & 7) << 4;

    int l = tid & 63, wv = tid >> 6;
    int wm = (wv & 1) * 32, wn = (wv >> 1) * 32;
    int lr = l & 15, lk = l >> 4;

    f32x4 acc0[2][2] = {};
    f32x4 acc1[2][2] = {};

    int4 rA0, rA1, rA2, rA3, rB0, rB1, rB2, rB3;
#define LOADG(kb) \
    rA0 = *(const int4*)(gAh + (kb));     rA1 = *(const int4*)(gAh + (kb) + 8); \
    rA2 = *(const int4*)(gAl + (kb));     rA3 = *(const int4*)(gAl + (kb) + 8); \
    rB0 = *(const int4*)(gBh + (kb));     rB1 = *(const int4*)(gBh + (kb) + 8); \
    rB2 = *(const int4*)(gBl + (kb));     rB3 = *(const int4*)(gBl + (kb) + 8);

    LOADG(0)

    #pragma unroll
    for (int kb = 0; kb < 256; kb += 64) {
        __syncthreads();
        *(int4*)(Ah + ((sbase +  0) ^ swz)) = rA0;
        *(int4*)(Ah + ((sbase + 16) ^ swz)) = rA1;
        *(int4*)(Al + ((sbase +  0) ^ swz)) = rA2;
        *(int4*)(Al + ((sbase + 16) ^ swz)) = rA3;
        *(int4*)(Bh + ((sbase +  0) ^ swz)) = rB0;
        *(int4*)(Bh + ((sbase + 16) ^ swz)) = rB1;
        *(int4*)(Bl + ((sbase +  0) ^ swz)) = rB2;
        *(int4*)(Bl + ((sbase + 16) ^ swz)) = rB3;
        __syncthreads();

        if (kb < 192) { LOADG(kb + 64) }

        #pragma unroll
        for (int kk = 0; kk < 2; ++kk) {
            int kby = kk * 64 + lk * 16;
            f16x8 fah[2], fal[2], fbh[2], fbl[2];
            #pragma unroll
            for (int mt = 0; mt < 2; ++mt) {
                int ml = wm + mt * 16 + lr;
                int off = (ml * 128 + kby) ^ ((ml & 7) << 4);
                fah[mt] = *(const f16x8*)(Ah + off);
                fal[mt] = *(const f16x8*)(Al + off);
            }
            #pragma unroll
            for (int nt = 0; nt < 2; ++nt) {
                int nl = wn + nt * 16 + lr;
                int off = (nl * 128 + kby) ^ ((nl & 7) << 4);
                fbh[nt] = *(const f16x8*)(Bh + off);
                fbl[nt] = *(const f16x8*)(Bl + off);
            }
            #pragma unroll
            for (int mt = 0; mt < 2; ++mt)
                #pragma unroll
                for (int nt = 0; nt < 2; ++nt) {
                    acc0[mt][nt] = __builtin_amdgcn_mfma_f32_16x16x32_f16(
                        fah[mt], fbh[nt], acc0[mt][nt], 0, 0, 0);
                    acc1[mt][nt] = __builtin_amdgcn_mfma_f32_16x16x32_f16(
                        fah[mt], fbl[nt], acc1[mt][nt], 0, 0, 0);
                    acc1[mt][nt] = __builtin_amdgcn_mfma_f32_16x16x32_f16(
                        fal[mt], fbh[nt], acc1[mt][nt], 0, 0, 0);
                }
        }
    }
#undef LOADG

    // epilogue: C/D layout col = lane&15, row = (lane>>4)*4 + q
    #pragma unroll
    for (int mt = 0; mt < 2; ++mt) {
        #pragma unroll
        for (int nt = 0; nt < 2; ++nt) {
            int n = nBase + wn + nt * 16 + lr;
            float bv = bias ? bias[n] : 0.0f;
            #pragma unroll
            for (int q = 0; q < 4; ++q) {
                int m = mBase + wm + mt * 16 + lk * 4 + q;
                size_t o = (size_t)m * 256 + n;
                float v = acc0[mt][nt][q] + acc1[mt][nt][q] * INV_SPLIT + bv;
                if (relu) v = fmaxf(v, 0.0f);
                if (Shi) v += (float)Shi[o] + (float)Slo[o] * INV_SPLIT;
                if (Cf32) {
                    Cf32[o] = v;
                } else {
                    _Float16 hh = (_Float16)v;
                    Chi[o] = hh;
                    Clo[o] = (_Float16)((v - (float)hh) * SPLIT_SCALE);
                }
            }
        }
    }
}

// ---------------------------------------------------------------------------
extern "C" void kernel_launch(void* const* d_in, const int* in_sizes, int n_in,
                              void* d_out, int out_size, void* d_ws, size_t ws_size,
                              hipStream_t stream)
{
    const float* x_in     = (const float*)d_in[0];
    const float* contacts = (const float*)d_in[1];
    const float* W_list   = (const float*)d_in[2];
    const float* dense_W  = (const float*)d_in[3];
    const float* dense_b  = (const float*)d_in[4];
    const float* final_W  = (const float*)d_in[5];
    const float* final_b  = (const float*)d_in[6];
    float* out = (float*)d_out;

    char* ws = (char*)d_ws;
    const size_t PL = (size_t)MROWS * DD;
    _Float16* pl[8];
    for (int i = 0; i < 8; ++i) pl[i] = (_Float16*)ws + (size_t)i * PL;
    char* p8 = ws + 8 * PL * sizeof(_Float16);
    int*   idx   = (int*)p8;
    int*   cnt   = (int*)(p8 + (size_t)MROWS * MAXNZ * sizeof(int));
    float* adiag = (float*)((char*)cnt + (size_t)MROWS * sizeof(int));
    _Float16* wt_hi = (_Float16*)((char*)adiag + (size_t)MROWS * sizeof(float));
    _Float16* wt_lo = wt_hi + (size_t)10 * 65536;

    setup_all<<<6160, 256, 0, stream>>>(W_list, dense_W, final_W, wt_hi, wt_lo,
                                        x_in, pl[0], pl[1],
                                        contacts, idx, cnt, adiag);

    dim3 gg(4, MROWS / 64);   // (4, 250) = 1000 blocks
    int cur = 0;
    for (int l = 0; l < LL; ++l) {
        int oth = 1 - cur;
        _Float16 *x0h = pl[2 * cur], *x0l = pl[2 * cur + 1];
        _Float16 *yh  = pl[2 * oth], *yl  = pl[2 * oth + 1];
        _Float16 *xah = pl[4], *xal = pl[5];
        _Float16 *xbh = pl[6], *xbl = pl[7];
        // y = x0 @ W_l
        gemm16<<<gg, 256, 0, stream>>>(x0h, x0l,
                                       wt_hi + (size_t)l * 65536,
                                       wt_lo + (size_t)l * 65536,
                                       nullptr, nullptr, nullptr,
                                       yh, yl, nullptr, 0);
        // sparse attention aggregate
        sparse_agg<<<MROWS / 4, 256, 0, stream>>>(yh, x0h, x0l, idx, cnt, adiag,
                                                  xah, xal);
        // dense 1 (relu)
        gemm16<<<gg, 256, 0, stream>>>(xah, xal,
                                       wt_hi + (size_t)(3 + l * 2) * 65536,
                                       wt_lo + (size_t)(3 + l * 2) * 65536,
                                       dense_b + (size_t)(l * 2 + 0) * 256,
                                       nullptr, nullptr,
                                       xbh, xbl, nullptr, 1);
        // dense 2 (relu) + skip(x0) -> next X0
        gemm16<<<gg, 256, 0, stream>>>(xbh, xbl,
                                       wt_hi + (size_t)(4 + l * 2) * 65536,
                                       wt_lo + (size_t)(4 + l * 2) * 65536,
                                       dense_b + (size_t)(l * 2 + 1) * 256,
                                       x0h, x0l,
                                       yh, yl, nullptr, 1);
        cur = oth;
    }
    // final projection -> fp32 d_out
    gemm16<<<gg, 256, 0, stream>>>(pl[2 * cur], pl[2 * cur + 1],
                                   wt_hi + (size_t)9 * 65536,
                                   wt_lo + (size_t)9 * 65536,
                                   final_b, nullptr, nullptr,
                                   nullptr, nullptr, out, 0);
}

// Round 11
// 286.005 us; speedup vs baseline: 1.4369x; 1.0595x over previous
//
#include <hip/hip_runtime.h>

#define BB 16
#define NN 1000
#define DD 256
#define LL 3
#define MAXNZ 256
#define MROWS (BB * NN)
#define SPLIT_SCALE 2048.0f
#define INV_SPLIT 4.8828125e-4f

typedef _Float16 f16x8 __attribute__((ext_vector_type(8)));
typedef _Float16 f16x2 __attribute__((ext_vector_type(2)));
typedef float f32x4 __attribute__((ext_vector_type(4)));

union H8 { f16x8 v; f16x2 p[4]; _Float16 h[8]; int4 i4; };

#if defined(__has_builtin)
#if __has_builtin(__builtin_amdgcn_fdot2)
#define HAS_FDOT2 1
#endif
#endif

__device__ __forceinline__ float dot2f(f16x2 a, f16x2 b, float c) {
#ifdef HAS_FDOT2
    return __builtin_amdgcn_fdot2(a, b, c, false);
#else
    return fmaf((float)a[0], (float)b[0], fmaf((float)a[1], (float)b[1], c));
#endif
}

// ---------------------------------------------------------------------------
// Kernel 0 (fused setup): [0,160) convert_w, [160,2160) convert_x,
// [2160,6160) build_sparse.
// ---------------------------------------------------------------------------
__global__ __launch_bounds__(256) void setup_all(
    const float* __restrict__ W_list, const float* __restrict__ dense_W,
    const float* __restrict__ final_W,
    _Float16* __restrict__ wt_hi, _Float16* __restrict__ wt_lo,
    const float* __restrict__ x_in,
    _Float16* __restrict__ xh, _Float16* __restrict__ xl,
    const float* __restrict__ contacts,
    int* __restrict__ idx, int* __restrict__ cnt, float* __restrict__ adiag)
{
    __shared__ float T[64][68];
    int bid = blockIdx.x;
    int t = threadIdx.x;

    if (bid < 160) {
        int mat = bid >> 4;
        int tile = bid & 15;
        int tk = (tile >> 2) * 64, tn = (tile & 3) * 64;
        const float* src = (mat < 3) ? (W_list + (size_t)mat * 65536)
                         : (mat < 9) ? (dense_W + (size_t)(mat - 3) * 65536)
                                     : final_W;
        {
            int k = t >> 2, nc = (t & 3) * 16;
            const float* sp = src + (size_t)(tk + k) * 256 + tn + nc;
            *(float4*)&T[k][nc + 0]  = *(const float4*)(sp + 0);
            *(float4*)&T[k][nc + 4]  = *(const float4*)(sp + 4);
            *(float4*)&T[k][nc + 8]  = *(const float4*)(sp + 8);
            *(float4*)&T[k][nc + 12] = *(const float4*)(sp + 12);
        }
        __syncthreads();
        int n = t >> 2, kc = (t & 3) * 16;
        H8 hh0, hh1, ll0, ll1;
        #pragma unroll
        for (int i = 0; i < 16; ++i) {
            float x = T[kc + i][n];
            _Float16 hi = (_Float16)x;
            _Float16 lo = (_Float16)((x - (float)hi) * SPLIT_SCALE);
            if (i < 8) { hh0.h[i] = hi; ll0.h[i] = lo; }
            else       { hh1.h[i - 8] = hi; ll1.h[i - 8] = lo; }
        }
        size_t o = (size_t)mat * 65536 + (size_t)(tn + n) * 256 + tk + kc;
        *(int4*)(wt_hi + o)     = hh0.i4;
        *(int4*)(wt_hi + o + 8) = hh1.i4;
        *(int4*)(wt_lo + o)     = ll0.i4;
        *(int4*)(wt_lo + o + 8) = ll1.i4;
    } else if (bid < 2160) {
        size_t gid = (size_t)(bid - 160) * 256 + t;
        const float* p = x_in + gid * 8;
        float4 a = *(const float4*)p;
        float4 b = *(const float4*)(p + 4);
        float xs[8] = {a.x, a.y, a.z, a.w, b.x, b.y, b.z, b.w};
        H8 hh, ll;
        #pragma unroll
        for (int i = 0; i < 8; ++i) {
            _Float16 h = (_Float16)xs[i];
            hh.h[i] = h;
            ll.h[i] = (_Float16)((xs[i] - (float)h) * SPLIT_SCALE);
        }
        *(int4*)(xh + gid * 8) = hh.i4;
        *(int4*)(xl + gid * 8) = ll.i4;
    } else {
        int wave = (int)(((size_t)(bid - 2160) * 256 + t) >> 6);
        int lane = t & 63;
        int b = wave / NN;
        int i = wave - b * NN;
        const float* row = contacts + (size_t)b * NN * NN + (size_t)i * NN;
        int* out = idx + (size_t)wave * MAXNZ;
        int count = 0;
        for (int j0 = 0; j0 < NN; j0 += 64) {
            int j = j0 + lane;
            float v = (j < NN) ? row[j] : 0.0f;
            bool p = (v != 0.0f) && (j != i);
            unsigned long long bal = __ballot(p);
            if (p) {
                int pre = __popcll(bal & ((1ull << lane) - 1ull));
                out[count + pre] = j;
            }
            count += __popcll(bal);
        }
        if (lane == 0) {
            cnt[wave] = count;
            adiag[wave] = row[i] + 1.0f;
        }
    }
}

// ---------------------------------------------------------------------------
// Kernel 2: sparse attention aggregate v7 — unroll-2 ILP.
// 1 wave per row; 16-lane group holds full 256-dim row (8+8 halves/lane).
// Per iteration 8 neighbors in TWO independent streams (A: 8t+g, B: 8t+4+g):
// two independent q-chains (each split in 2 halves) -> 4 parallel dot chains,
// 8 interleavable shfls, 2 exps. Data loaded at t for t+1.
// ---------------------------------------------------------------------------
__global__ __launch_bounds__(256, 3) void sparse_agg(
    const _Float16* __restrict__ yhi,
    const _Float16* __restrict__ xhi, const _Float16* __restrict__ xlo,
    const int* __restrict__ idx, const int* __restrict__ cnt,
    const float* __restrict__ adiag,
    _Float16* __restrict__ ohi, _Float16* __restrict__ olo)
{
    int bid = blockIdx.x;
    int xcd = bid & 7;
    int chunk = bid >> 3;
    int row = xcd * 2000 + chunk * 4 + (int)(threadIdx.x >> 6);
    row = __builtin_amdgcn_readfirstlane(row);
    int lane = threadIdx.x & 63;
    int g = lane >> 4, s = lane & 15;
    int b = row / NN;

    const _Float16* yp = yhi + (size_t)row * DD + s * 8;
    H8 yh0, yh1;
    yh0.i4 = *(const int4*)yp;
    yh1.i4 = *(const int4*)(yp + 128);

    const _Float16* xph = xhi + (size_t)row * DD + s * 8;
    const _Float16* xpl = xlo + (size_t)row * DD + s * 8;
    H8 xih0, xih1, xil0, xil1;
    xih0.i4 = *(const int4*)xph;       xih1.i4 = *(const int4*)(xph + 128);
    xil0.i4 = *(const int4*)xpl;       xil1.i4 = *(const int4*)(xpl + 128);
    float xi[16];
    #pragma unroll
    for (int u = 0; u < 8; ++u) {
        xi[u]     = fmaf((float)xil0.h[u], INV_SPLIT, (float)xih0.h[u]);
        xi[8 + u] = fmaf((float)xil1.h[u], INV_SPLIT, (float)xih1.h[u]);
    }
    const _Float16* xb = xhi + (size_t)b * NN * DD;

    float p = 0.0f;
    #pragma unroll
    for (int u = 0; u < 8; ++u) {
        p = fmaf((float)yh0.h[u], xi[u], p);
        p = fmaf((float)yh1.h[u], xi[8 + u], p);
    }
    p += __shfl_xor(p, 1); p += __shfl_xor(p, 2);
    p += __shfl_xor(p, 4); p += __shfl_xor(p, 8);
    float wd = (g == 0) ? (__expf(p) + 1e-5f) * adiag[row] : 0.0f;
    float denom = wd;
    float acc[16];
    #pragma unroll
    for (int u = 0; u < 16; ++u) acc[u] = wd * xi[u];

    const int c = cnt[row];
    const int* ip = idx + (size_t)row * MAXNZ;
    const int iters = (c + 7) >> 3;

    // prologue: data for t=0 (both streams), idx for t=1
    int jA1, jB1;
    H8 vA0, vA1, vB0, vB1;
    {
        int ja = (g < c) ? ip[g] : 0;
        int jb = (4 + g < c) ? ip[4 + g] : 0;
        jA1 = (8 + g < c) ? ip[8 + g] : 0;
        jB1 = (12 + g < c) ? ip[12 + g] : 0;
        const _Float16* pa = xb + (size_t)ja * DD + s * 8;
        vA0.i4 = *(const int4*)pa;
        vA1.i4 = *(const int4*)(pa + 128);
        const _Float16* pb = xb + (size_t)jb * DD + s * 8;
        vB0.i4 = *(const int4*)pb;
        vB1.i4 = *(const int4*)(pb + 128);
    }

    for (int t = 0; t < iters; ++t) {
        // issue: idx for t+2, data for t+1
        int k2a = (t + 2) * 8 + g;
        int k2b = k2a + 4;
        int jA2 = (k2a < c) ? ip[k2a] : 0;
        int jB2 = (k2b < c) ? ip[k2b] : 0;
        H8 mA0, mA1, mB0, mB1;
        const _Float16* pa = xb + (size_t)jA1 * DD + s * 8;
        mA0.i4 = *(const int4*)pa;
        mA1.i4 = *(const int4*)(pa + 128);
        const _Float16* pb = xb + (size_t)jB1 * DD + s * 8;
        mB0.i4 = *(const int4*)pb;
        mB1.i4 = *(const int4*)(pb + 128);

        bool vokA = t * 8 + g < c;
        bool vokB = t * 8 + 4 + g < c;

        // two independent q-chains, each split into two halves
        float qa0 = 0.0f, qa1 = 0.0f, qb0 = 0.0f, qb1 = 0.0f;
        #pragma unroll
        for (int i = 0; i < 4; ++i) {
            qa0 = dot2f(yh0.p[i], vA0.p[i], qa0);
            qa1 = dot2f(yh1.p[i], vA1.p[i], qa1);
            qb0 = dot2f(yh0.p[i], vB0.p[i], qb0);
            qb1 = dot2f(yh1.p[i], vB1.p[i], qb1);
        }
        float qa = qa0 + qa1, qb = qb0 + qb1;
        qa += __shfl_xor(qa, 1); qb += __shfl_xor(qb, 1);
        qa += __shfl_xor(qa, 2); qb += __shfl_xor(qb, 2);
        qa += __shfl_xor(qa, 4); qb += __shfl_xor(qb, 4);
        qa += __shfl_xor(qa, 8); qb += __shfl_xor(qb, 8);
        float wa = vokA ? __expf(qa) : 0.0f;
        float wb = vokB ? __expf(qb) : 0.0f;
        denom += wa + wb;
        #pragma unroll
        for (int u = 0; u < 8; ++u) {
            acc[u]     = fmaf(wa, (float)vA0.h[u], acc[u]);
            acc[8 + u] = fmaf(wa, (float)vA1.h[u], acc[8 + u]);
        }
        #pragma unroll
        for (int u = 0; u < 8; ++u) {
            acc[u]     = fmaf(wb, (float)vB0.h[u], acc[u]);
            acc[8 + u] = fmaf(wb, (float)vB1.h[u], acc[8 + u]);
        }

        vA0 = mA0; vA1 = mA1; vB0 = mB0; vB1 = mB1;
        jA1 = jA2; jB1 = jB2;
    }

#define XG(x) x += __shfl_xor(x, 16); x += __shfl_xor(x, 32);
    XG(denom);
    #pragma unroll
    for (int u = 0; u < 16; ++u) { XG(acc[u]) }
#undef XG

    float inv = 1.0f / denom;
    int half = (g & 1) * 8;
    H8 st;
    #pragma unroll
    for (int i = 0; i < 8; ++i) {
        float x = acc[half + i] * inv;
        _Float16 h = (_Float16)x;
        st.h[i] = (g & 2) ? (_Float16)((x - (float)h) * SPLIT_SCALE) : h;
    }
    _Float16* dst = ((g & 2) ? olo : ohi) + (size_t)row * DD + (g & 1) * 128 + s * 8;
    *(int4*)dst = st.i4;
}

// ---------------------------------------------------------------------------
// Kernel 3: split-fp16 MFMA GEMM v7.
// BM=BN=64, BK=64; 4 waves, wave tile 32x32; reg prefetch of next K-tile.
// NEW: epilogue repacks acc through LDS (fp32 [64][68]) then does fully
// coalesced int4 loads/stores for bias/skip/output; lo-plane write optional.
// ---------------------------------------------------------------------------
__global__ __launch_bounds__(256, 3) void gemm16(
    const _Float16* __restrict__ Ahi, const _Float16* __restrict__ Alo,
    const _Float16* __restrict__ Bhi, const _Float16* __restrict__ Blo,
    const float* __restrict__ bias,
    const _Float16* __restrict__ Shi, const _Float16* __restrict__ Slo,
    _Float16* __restrict__ Chi, _Float16* __restrict__ Clo,
    float* __restrict__ Cf32, int relu, int lo_write)
{
    __shared__ __align__(16) char smem[32768];
    char* Ah = smem;
    char* Al = smem + 8192;
    char* Bh = smem + 16384;
    char* Bl = smem + 24576;

    int tid = threadIdx.x;
    int mBase = blockIdx.y * 64;
    int nBase = blockIdx.x * 64;

    int r = tid >> 2;
    int kc = (tid & 3) * 16;
    const _Float16* gAh = Ahi + (size_t)(mBase + r) * 256 + kc;
    const _Float16* gAl = Alo + (size_t)(mBase + r) * 256 + kc;
    const _Float16* gBh = Bhi + (size_t)(nBase + r) * 256 + kc;
    const _Float16* gBl = Blo + (size_t)(nBase + r) * 256 + kc;
    int sbase = r * 128 + kc * 2;
    int swz = (r & 7) << 4;

    int l = tid & 63, wv = tid >> 6;
    int wm = (wv & 1) * 32, wn = (wv >> 1) * 32;
    int lr = l & 15, lk = l >> 4;

    f32x4 acc0[2][2] = {};
    f32x4 acc1[2][2] = {};

    int4 rA0, rA1, rA2, rA3, rB0, rB1, rB2, rB3;
#define LOADG(kb) \
    rA0 = *(const int4*)(gAh + (kb));     rA1 = *(const int4*)(gAh + (kb) + 8); \
    rA2 = *(const int4*)(gAl + (kb));     rA3 = *(const int4*)(gAl + (kb) + 8); \
    rB0 = *(const int4*)(gBh + (kb));     rB1 = *(const int4*)(gBh + (kb) + 8); \
    rB2 = *(const int4*)(gBl + (kb));     rB3 = *(const int4*)(gBl + (kb) + 8);

    LOADG(0)

    #pragma unroll
    for (int kb = 0; kb < 256; kb += 64) {
        __syncthreads();
        *(int4*)(Ah + ((sbase +  0) ^ swz)) = rA0;
        *(int4*)(Ah + ((sbase + 16) ^ swz)) = rA1;
        *(int4*)(Al + ((sbase +  0) ^ swz)) = rA2;
        *(int4*)(Al + ((sbase + 16) ^ swz)) = rA3;
        *(int4*)(Bh + ((sbase +  0) ^ swz)) = rB0;
        *(int4*)(Bh + ((sbase + 16) ^ swz)) = rB1;
        *(int4*)(Bl + ((sbase +  0) ^ swz)) = rB2;
        *(int4*)(Bl + ((sbase + 16) ^ swz)) = rB3;
        __syncthreads();

        if (kb < 192) { LOADG(kb + 64) }

        #pragma unroll
        for (int kk = 0; kk < 2; ++kk) {
            int kby = kk * 64 + lk * 16;
            f16x8 fah[2], fal[2], fbh[2], fbl[2];
            #pragma unroll
            for (int mt = 0; mt < 2; ++mt) {
                int ml = wm + mt * 16 + lr;
                int off = (ml * 128 + kby) ^ ((ml & 7) << 4);
                fah[mt] = *(const f16x8*)(Ah + off);
                fal[mt] = *(const f16x8*)(Al + off);
            }
            #pragma unroll
            for (int nt = 0; nt < 2; ++nt) {
                int nl = wn + nt * 16 + lr;
                int off = (nl * 128 + kby) ^ ((nl & 7) << 4);
                fbh[nt] = *(const f16x8*)(Bh + off);
                fbl[nt] = *(const f16x8*)(Bl + off);
            }
            #pragma unroll
            for (int mt = 0; mt < 2; ++mt)
                #pragma unroll
                for (int nt = 0; nt < 2; ++nt) {
                    acc0[mt][nt] = __builtin_amdgcn_mfma_f32_16x16x32_f16(
                        fah[mt], fbh[nt], acc0[mt][nt], 0, 0, 0);
                    acc1[mt][nt] = __builtin_amdgcn_mfma_f32_16x16x32_f16(
                        fah[mt], fbl[nt], acc1[mt][nt], 0, 0, 0);
                    acc1[mt][nt] = __builtin_amdgcn_mfma_f32_16x16x32_f16(
                        fal[mt], fbh[nt], acc1[mt][nt], 0, 0, 0);
                }
        }
    }
#undef LOADG

    // ---- epilogue: repack through LDS, coalesced I/O ----
    __syncthreads();
    float* T = (float*)smem;              // [64][68] fp32, 17.4 KB
    #pragma unroll
    for (int mt = 0; mt < 2; ++mt)
        #pragma unroll
        for (int nt = 0; nt < 2; ++nt)
            #pragma unroll
            for (int q = 0; q < 4; ++q) {
                int m = wm + mt * 16 + lk * 4 + q;
                int n = wn + nt * 16 + lr;
                T[m * 68 + n] = acc0[mt][nt][q] + acc1[mt][nt][q] * INV_SPLIT;
            }
    __syncthreads();

    {
        int rr = tid >> 2;                // out row 0..63
        int c0 = (tid & 3) * 16;          // 16 consecutive cols
        int m = mBase + rr;
        size_t o = (size_t)m * 256 + nBase + c0;
        float v[16];
        #pragma unroll
        for (int i = 0; i < 4; ++i) {
            float4 f = *(const float4*)&T[rr * 68 + c0 + i * 4];
            v[i * 4 + 0] = f.x; v[i * 4 + 1] = f.y;
            v[i * 4 + 2] = f.z; v[i * 4 + 3] = f.w;
        }
        if (bias) {
            #pragma unroll
            for (int i = 0; i < 4; ++i) {
                float4 bv = *(const float4*)(bias + nBase + c0 + i * 4);
                v[i * 4 + 0] += bv.x; v[i * 4 + 1] += bv.y;
                v[i * 4 + 2] += bv.z; v[i * 4 + 3] += bv.w;
            }
        }
        if (relu) {
            #pragma unroll
            for (int i = 0; i < 16; ++i) v[i] = fmaxf(v[i], 0.0f);
        }
        if (Shi) {
            #pragma unroll
            for (int j = 0; j < 2; ++j) {
                H8 sh, sl;
                sh.i4 = *(const int4*)(Shi + o + j * 8);
                sl.i4 = *(const int4*)(Slo + o + j * 8);
                #pragma unroll
                for (int u = 0; u < 8; ++u)
                    v[j * 8 + u] += fmaf((float)sl.h[u], INV_SPLIT, (float)sh.h[u]);
            }
        }
        if (Cf32) {
            #pragma unroll
            for (int i = 0; i < 4; ++i) {
                *(float4*)(Cf32 + o + i * 4) =
                    make_float4(v[i * 4], v[i * 4 + 1], v[i * 4 + 2], v[i * 4 + 3]);
            }
        } else {
            #pragma unroll
            for (int j = 0; j < 2; ++j) {
                H8 hh;
                #pragma unroll
                for (int u = 0; u < 8; ++u) hh.h[u] = (_Float16)v[j * 8 + u];
                *(int4*)(Chi + o + j * 8) = hh.i4;
            }
            if (lo_write) {
                #pragma unroll
                for (int j = 0; j < 2; ++j) {
                    H8 ll;
                    #pragma unroll
                    for (int u = 0; u < 8; ++u) {
                        float x = v[j * 8 + u];
                        ll.h[u] = (_Float16)((x - (float)(_Float16)x) * SPLIT_SCALE);
                    }
                    *(int4*)(Clo + o + j * 8) = ll.i4;
                }
            }
        }
    }
}

// ---------------------------------------------------------------------------
extern "C" void kernel_launch(void* const* d_in, const int* in_sizes, int n_in,
                              void* d_out, int out_size, void* d_ws, size_t ws_size,
                              hipStream_t stream)
{
    const float* x_in     = (const float*)d_in[0];
    const float* contacts = (const float*)d_in[1];
    const float* W_list   = (const float*)d_in[2];
    const float* dense_W  = (const float*)d_in[3];
    const float* dense_b  = (const float*)d_in[4];
    const float* final_W  = (const float*)d_in[5];
    const float* final_b  = (const float*)d_in[6];
    float* out = (float*)d_out;

    char* ws = (char*)d_ws;
    const size_t PL = (size_t)MROWS * DD;
    _Float16* pl[8];
    for (int i = 0; i < 8; ++i) pl[i] = (_Float16*)ws + (size_t)i * PL;
    char* p8 = ws + 8 * PL * sizeof(_Float16);
    int*   idx   = (int*)p8;
    int*   cnt   = (int*)(p8 + (size_t)MROWS * MAXNZ * sizeof(int));
    float* adiag = (float*)((char*)cnt + (size_t)MROWS * sizeof(int));
    _Float16* wt_hi = (_Float16*)((char*)adiag + (size_t)MROWS * sizeof(float));
    _Float16* wt_lo = wt_hi + (size_t)10 * 65536;

    setup_all<<<6160, 256, 0, stream>>>(W_list, dense_W, final_W, wt_hi, wt_lo,
                                        x_in, pl[0], pl[1],
                                        contacts, idx, cnt, adiag);

    dim3 gg(4, MROWS / 64);   // (4, 250) = 1000 blocks
    int cur = 0;
    for (int l = 0; l < LL; ++l) {
        int oth = 1 - cur;
        _Float16 *x0h = pl[2 * cur], *x0l = pl[2 * cur + 1];
        _Float16 *yh  = pl[2 * oth], *yl  = pl[2 * oth + 1];
        _Float16 *xah = pl[4], *xal = pl[5];
        _Float16 *xbh = pl[6], *xbl = pl[7];
        // y = x0 @ W_l (hi only — scores tolerate fp16)
        gemm16<<<gg, 256, 0, stream>>>(x0h, x0l,
                                       wt_hi + (size_t)l * 65536,
                                       wt_lo + (size_t)l * 65536,
                                       nullptr, nullptr, nullptr,
                                       yh, yl, nullptr, 0, 0);
        // sparse attention aggregate
        sparse_agg<<<MROWS / 4, 256, 0, stream>>>(yh, x0h, x0l, idx, cnt, adiag,
                                                  xah, xal);
        // dense 1 (relu)
        gemm16<<<gg, 256, 0, stream>>>(xah, xal,
                                       wt_hi + (size_t)(3 + l * 2) * 65536,
                                       wt_lo + (size_t)(3 + l * 2) * 65536,
                                       dense_b + (size_t)(l * 2 + 0) * 256,
                                       nullptr, nullptr,
                                       xbh, xbl, nullptr, 1, 1);
        // dense 2 (relu) + skip(x0) -> next X0
        gemm16<<<gg, 256, 0, stream>>>(xbh, xbl,
                                       wt_hi + (size_t)(4 + l * 2) * 65536,
                                       wt_lo + (size_t)(4 + l * 2) * 65536,
                                       dense_b + (size_t)(l * 2 + 1) * 256,
                                       x0h, x0l,
                                       yh, yl, nullptr, 1, 1);
        cur = oth;
    }
    // final projection -> fp32 d_out
    gemm16<<<gg, 256, 0, stream>>>(pl[2 * cur], pl[2 * cur + 1],
                                   wt_hi + (size_t)9 * 65536,
                                   wt_lo + (size_t)9 * 65536,
                                   final_b, nullptr, nullptr,
                                   nullptr, nullptr, out, 0, 0);
}

// Round 12
// 279.702 us; speedup vs baseline: 1.4693x; 1.0225x over previous
//
#include <hip/hip_runtime.h>

#define BB 16
#define NN 1000
#define DD 256
#define LL 3
#define MAXNZ 256
#define MROWS (BB * NN)
#define SPLIT_SCALE 2048.0f
#define INV_SPLIT 4.8828125e-4f

typedef _Float16 f16x8 __attribute__((ext_vector_type(8)));
typedef _Float16 f16x2 __attribute__((ext_vector_type(2)));
typedef float f32x4 __attribute__((ext_vector_type(4)));

union H8 { f16x8 v; f16x2 p[4]; _Float16 h[8]; int4 i4; };

#if defined(__has_builtin)
#if __has_builtin(__builtin_amdgcn_fdot2)
#define HAS_FDOT2 1
#endif
#endif

__device__ __forceinline__ float dot2f(f16x2 a, f16x2 b, float c) {
#ifdef HAS_FDOT2
    return __builtin_amdgcn_fdot2(a, b, c, false);
#else
    return fmaf((float)a[0], (float)b[0], fmaf((float)a[1], (float)b[1], c));
#endif
}

// ---------------------------------------------------------------------------
// Kernel 0 (fused setup): [0,160) convert_w, [160,2160) convert_x,
// [2160,6160) build_sparse.
// ---------------------------------------------------------------------------
__global__ __launch_bounds__(256) void setup_all(
    const float* __restrict__ W_list, const float* __restrict__ dense_W,
    const float* __restrict__ final_W,
    _Float16* __restrict__ wt_hi, _Float16* __restrict__ wt_lo,
    const float* __restrict__ x_in,
    _Float16* __restrict__ xh, _Float16* __restrict__ xl,
    const float* __restrict__ contacts,
    int* __restrict__ idx, int* __restrict__ cnt, float* __restrict__ adiag)
{
    __shared__ float T[64][68];
    int bid = blockIdx.x;
    int t = threadIdx.x;

    if (bid < 160) {
        int mat = bid >> 4;
        int tile = bid & 15;
        int tk = (tile >> 2) * 64, tn = (tile & 3) * 64;
        const float* src = (mat < 3) ? (W_list + (size_t)mat * 65536)
                         : (mat < 9) ? (dense_W + (size_t)(mat - 3) * 65536)
                                     : final_W;
        {
            int k = t >> 2, nc = (t & 3) * 16;
            const float* sp = src + (size_t)(tk + k) * 256 + tn + nc;
            *(float4*)&T[k][nc + 0]  = *(const float4*)(sp + 0);
            *(float4*)&T[k][nc + 4]  = *(const float4*)(sp + 4);
            *(float4*)&T[k][nc + 8]  = *(const float4*)(sp + 8);
            *(float4*)&T[k][nc + 12] = *(const float4*)(sp + 12);
        }
        __syncthreads();
        int n = t >> 2, kc = (t & 3) * 16;
        H8 hh0, hh1, ll0, ll1;
        #pragma unroll
        for (int i = 0; i < 16; ++i) {
            float x = T[kc + i][n];
            _Float16 hi = (_Float16)x;
            _Float16 lo = (_Float16)((x - (float)hi) * SPLIT_SCALE);
            if (i < 8) { hh0.h[i] = hi; ll0.h[i] = lo; }
            else       { hh1.h[i - 8] = hi; ll1.h[i - 8] = lo; }
        }
        size_t o = (size_t)mat * 65536 + (size_t)(tn + n) * 256 + tk + kc;
        *(int4*)(wt_hi + o)     = hh0.i4;
        *(int4*)(wt_hi + o + 8) = hh1.i4;
        *(int4*)(wt_lo + o)     = ll0.i4;
        *(int4*)(wt_lo + o + 8) = ll1.i4;
    } else if (bid < 2160) {
        size_t gid = (size_t)(bid - 160) * 256 + t;
        const float* p = x_in + gid * 8;
        float4 a = *(const float4*)p;
        float4 b = *(const float4*)(p + 4);
        float xs[8] = {a.x, a.y, a.z, a.w, b.x, b.y, b.z, b.w};
        H8 hh, ll;
        #pragma unroll
        for (int i = 0; i < 8; ++i) {
            _Float16 h = (_Float16)xs[i];
            hh.h[i] = h;
            ll.h[i] = (_Float16)((xs[i] - (float)h) * SPLIT_SCALE);
        }
        *(int4*)(xh + gid * 8) = hh.i4;
        *(int4*)(xl + gid * 8) = ll.i4;
    } else {
        int wave = (int)(((size_t)(bid - 2160) * 256 + t) >> 6);
        int lane = t & 63;
        int b = wave / NN;
        int i = wave - b * NN;
        const float* row = contacts + (size_t)b * NN * NN + (size_t)i * NN;
        int* out = idx + (size_t)wave * MAXNZ;
        int count = 0;
        for (int j0 = 0; j0 < NN; j0 += 64) {
            int j = j0 + lane;
            float v = (j < NN) ? row[j] : 0.0f;
            bool p = (v != 0.0f) && (j != i);
            unsigned long long bal = __ballot(p);
            if (p) {
                int pre = __popcll(bal & ((1ull << lane) - 1ull));
                out[count + pre] = j;
            }
            count += __popcll(bal);
        }
        if (lane == 0) {
            cnt[wave] = count;
            adiag[wave] = row[i] + 1.0f;
        }
    }
}

// ---------------------------------------------------------------------------
// Kernel 2: sparse attention aggregate v7 (round-11, frozen).
// ---------------------------------------------------------------------------
__global__ __launch_bounds__(256, 3) void sparse_agg(
    const _Float16* __restrict__ yhi,
    const _Float16* __restrict__ xhi, const _Float16* __restrict__ xlo,
    const int* __restrict__ idx, const int* __restrict__ cnt,
    const float* __restrict__ adiag,
    _Float16* __restrict__ ohi, _Float16* __restrict__ olo)
{
    int bid = blockIdx.x;
    int xcd = bid & 7;
    int chunk = bid >> 3;
    int row = xcd * 2000 + chunk * 4 + (int)(threadIdx.x >> 6);
    row = __builtin_amdgcn_readfirstlane(row);
    int lane = threadIdx.x & 63;
    int g = lane >> 4, s = lane & 15;
    int b = row / NN;

    const _Float16* yp = yhi + (size_t)row * DD + s * 8;
    H8 yh0, yh1;
    yh0.i4 = *(const int4*)yp;
    yh1.i4 = *(const int4*)(yp + 128);

    const _Float16* xph = xhi + (size_t)row * DD + s * 8;
    const _Float16* xpl = xlo + (size_t)row * DD + s * 8;
    H8 xih0, xih1, xil0, xil1;
    xih0.i4 = *(const int4*)xph;       xih1.i4 = *(const int4*)(xph + 128);
    xil0.i4 = *(const int4*)xpl;       xil1.i4 = *(const int4*)(xpl + 128);
    float xi[16];
    #pragma unroll
    for (int u = 0; u < 8; ++u) {
        xi[u]     = fmaf((float)xil0.h[u], INV_SPLIT, (float)xih0.h[u]);
        xi[8 + u] = fmaf((float)xil1.h[u], INV_SPLIT, (float)xih1.h[u]);
    }
    const _Float16* xb = xhi + (size_t)b * NN * DD;

    float p = 0.0f;
    #pragma unroll
    for (int u = 0; u < 8; ++u) {
        p = fmaf((float)yh0.h[u], xi[u], p);
        p = fmaf((float)yh1.h[u], xi[8 + u], p);
    }
    p += __shfl_xor(p, 1); p += __shfl_xor(p, 2);
    p += __shfl_xor(p, 4); p += __shfl_xor(p, 8);
    float wd = (g == 0) ? (__expf(p) + 1e-5f) * adiag[row] : 0.0f;
    float denom = wd;
    float acc[16];
    #pragma unroll
    for (int u = 0; u < 16; ++u) acc[u] = wd * xi[u];

    const int c = cnt[row];
    const int* ip = idx + (size_t)row * MAXNZ;
    const int iters = (c + 7) >> 3;

    int jA1, jB1;
    H8 vA0, vA1, vB0, vB1;
    {
        int ja = (g < c) ? ip[g] : 0;
        int jb = (4 + g < c) ? ip[4 + g] : 0;
        jA1 = (8 + g < c) ? ip[8 + g] : 0;
        jB1 = (12 + g < c) ? ip[12 + g] : 0;
        const _Float16* pa = xb + (size_t)ja * DD + s * 8;
        vA0.i4 = *(const int4*)pa;
        vA1.i4 = *(const int4*)(pa + 128);
        const _Float16* pb = xb + (size_t)jb * DD + s * 8;
        vB0.i4 = *(const int4*)pb;
        vB1.i4 = *(const int4*)(pb + 128);
    }

    for (int t = 0; t < iters; ++t) {
        int k2a = (t + 2) * 8 + g;
        int k2b = k2a + 4;
        int jA2 = (k2a < c) ? ip[k2a] : 0;
        int jB2 = (k2b < c) ? ip[k2b] : 0;
        H8 mA0, mA1, mB0, mB1;
        const _Float16* pa = xb + (size_t)jA1 * DD + s * 8;
        mA0.i4 = *(const int4*)pa;
        mA1.i4 = *(const int4*)(pa + 128);
        const _Float16* pb = xb + (size_t)jB1 * DD + s * 8;
        mB0.i4 = *(const int4*)pb;
        mB1.i4 = *(const int4*)(pb + 128);

        bool vokA = t * 8 + g < c;
        bool vokB = t * 8 + 4 + g < c;

        float qa0 = 0.0f, qa1 = 0.0f, qb0 = 0.0f, qb1 = 0.0f;
        #pragma unroll
        for (int i = 0; i < 4; ++i) {
            qa0 = dot2f(yh0.p[i], vA0.p[i], qa0);
            qa1 = dot2f(yh1.p[i], vA1.p[i], qa1);
            qb0 = dot2f(yh0.p[i], vB0.p[i], qb0);
            qb1 = dot2f(yh1.p[i], vB1.p[i], qb1);
        }
        float qa = qa0 + qa1, qb = qb0 + qb1;
        qa += __shfl_xor(qa, 1); qb += __shfl_xor(qb, 1);
        qa += __shfl_xor(qa, 2); qb += __shfl_xor(qb, 2);
        qa += __shfl_xor(qa, 4); qb += __shfl_xor(qb, 4);
        qa += __shfl_xor(qa, 8); qb += __shfl_xor(qb, 8);
        float wa = vokA ? __expf(qa) : 0.0f;
        float wb = vokB ? __expf(qb) : 0.0f;
        denom += wa + wb;
        #pragma unroll
        for (int u = 0; u < 8; ++u) {
            acc[u]     = fmaf(wa, (float)vA0.h[u], acc[u]);
            acc[8 + u] = fmaf(wa, (float)vA1.h[u], acc[8 + u]);
        }
        #pragma unroll
        for (int u = 0; u < 8; ++u) {
            acc[u]     = fmaf(wb, (float)vB0.h[u], acc[u]);
            acc[8 + u] = fmaf(wb, (float)vB1.h[u], acc[8 + u]);
        }

        vA0 = mA0; vA1 = mA1; vB0 = mB0; vB1 = mB1;
        jA1 = jA2; jB1 = jB2;
    }

#define XG(x) x += __shfl_xor(x, 16); x += __shfl_xor(x, 32);
    XG(denom);
    #pragma unroll
    for (int u = 0; u < 16; ++u) { XG(acc[u]) }
#undef XG

    float inv = 1.0f / denom;
    int half = (g & 1) * 8;
    H8 st;
    #pragma unroll
    for (int i = 0; i < 8; ++i) {
        float x = acc[half + i] * inv;
        _Float16 h = (_Float16)x;
        st.h[i] = (g & 2) ? (_Float16)((x - (float)h) * SPLIT_SCALE) : h;
    }
    _Float16* dst = ((g & 2) ? olo : ohi) + (size_t)row * DD + (g & 1) * 128 + s * 8;
    *(int4*)dst = st.i4;
}

// ---------------------------------------------------------------------------
// Kernel 3: split-fp16 MFMA GEMM v8 — BM=128 halves W re-read traffic.
// BM=128, BN=64, BK=64; 512 threads = 8 waves (4m x 2n), wave tile 32x32.
// W traffic/dispatch: (16000/128) x 256KB = 32 MB (was 64).
// Reg prefetch of next K-tile (A 4 int4 + B 2 int4); LDS 48KB swizzled.
// ~114 VGPR -> __launch_bounds__(512,4): 4 waves/SIMD, 2 blocks/CU.
// ---------------------------------------------------------------------------
__global__ __launch_bounds__(512, 4) void gemm16(
    const _Float16* __restrict__ Ahi, const _Float16* __restrict__ Alo,
    const _Float16* __restrict__ Bhi, const _Float16* __restrict__ Blo,
    const float* __restrict__ bias,
    const _Float16* __restrict__ Shi, const _Float16* __restrict__ Slo,
    _Float16* __restrict__ Chi, _Float16* __restrict__ Clo,
    float* __restrict__ Cf32, int relu, int lo_write)
{
    __shared__ __align__(16) char smem[49152];
    char* Ah = smem;              // [128 m][64 k] halves swz, 16 KB
    char* Al = smem + 16384;
    char* Bh = smem + 32768;      // [64 n][64 k], 8 KB
    char* Bl = smem + 40960;

    int tid = threadIdx.x;
    int mBase = blockIdx.y * 128;
    int nBase = blockIdx.x * 64;

    // A staging: row 0..127, k-chunk of 16 halves
    int ra = tid >> 2, ka = (tid & 3) * 16;
    const _Float16* gAh = Ahi + (size_t)(mBase + ra) * 256 + ka;
    const _Float16* gAl = Alo + (size_t)(mBase + ra) * 256 + ka;
    int sbA = ra * 128 + ka * 2, swzA = (ra & 7) << 4;
    // B staging: row 0..63, k-chunk of 8 halves
    int rb = tid >> 3, kbb = (tid & 7) * 8;
    const _Float16* gBh = Bhi + (size_t)(nBase + rb) * 256 + kbb;
    const _Float16* gBl = Blo + (size_t)(nBase + rb) * 256 + kbb;
    int sbB = rb * 128 + kbb * 2, swzB = (rb & 7) << 4;

    int l = tid & 63, wv = tid >> 6;
    int wm = (wv & 3) * 32, wn = (wv >> 2) * 32;
    int lr = l & 15, lk = l >> 4;

    f32x4 acc0[2][2] = {};
    f32x4 acc1[2][2] = {};

    int4 rA0, rA1, rA2, rA3, rB0, rB1;
#define LOADG(kb) \
    rA0 = *(const int4*)(gAh + (kb));     rA1 = *(const int4*)(gAh + (kb) + 8); \
    rA2 = *(const int4*)(gAl + (kb));     rA3 = *(const int4*)(gAl + (kb) + 8); \
    rB0 = *(const int4*)(gBh + (kb));     rB1 = *(const int4*)(gBl + (kb));

    LOADG(0)

    #pragma unroll
    for (int kb = 0; kb < 256; kb += 64) {
        __syncthreads();
        *(int4*)(Ah + ((sbA +  0) ^ swzA)) = rA0;
        *(int4*)(Ah + ((sbA + 16) ^ swzA)) = rA1;
        *(int4*)(Al + ((sbA +  0) ^ swzA)) = rA2;
        *(int4*)(Al + ((sbA + 16) ^ swzA)) = rA3;
        *(int4*)(Bh + (sbB ^ swzB)) = rB0;
        *(int4*)(Bl + (sbB ^ swzB)) = rB1;
        __syncthreads();

        if (kb < 192) { LOADG(kb + 64) }

        #pragma unroll
        for (int kk = 0; kk < 2; ++kk) {
            int kby = kk * 64 + lk * 16;
            f16x8 fah[2], fal[2], fbh[2], fbl[2];
            #pragma unroll
            for (int mt = 0; mt < 2; ++mt) {
                int ml = wm + mt * 16 + lr;
                int off = (ml * 128 + kby) ^ ((ml & 7) << 4);
                fah[mt] = *(const f16x8*)(Ah + off);
                fal[mt] = *(const f16x8*)(Al + off);
            }
            #pragma unroll
            for (int nt = 0; nt < 2; ++nt) {
                int nl = wn + nt * 16 + lr;
                int off = (nl * 128 + kby) ^ ((nl & 7) << 4);
                fbh[nt] = *(const f16x8*)(Bh + off);
                fbl[nt] = *(const f16x8*)(Bl + off);
            }
            #pragma unroll
            for (int mt = 0; mt < 2; ++mt)
                #pragma unroll
                for (int nt = 0; nt < 2; ++nt) {
                    acc0[mt][nt] = __builtin_amdgcn_mfma_f32_16x16x32_f16(
                        fah[mt], fbh[nt], acc0[mt][nt], 0, 0, 0);
                    acc1[mt][nt] = __builtin_amdgcn_mfma_f32_16x16x32_f16(
                        fah[mt], fbl[nt], acc1[mt][nt], 0, 0, 0);
                    acc1[mt][nt] = __builtin_amdgcn_mfma_f32_16x16x32_f16(
                        fal[mt], fbh[nt], acc1[mt][nt], 0, 0, 0);
                }
        }
    }
#undef LOADG

    // ---- epilogue: repack through LDS, coalesced I/O ----
    __syncthreads();
    float* T = (float*)smem;              // [128][68] fp32, 34.8 KB
    #pragma unroll
    for (int mt = 0; mt < 2; ++mt)
        #pragma unroll
        for (int nt = 0; nt < 2; ++nt)
            #pragma unroll
            for (int q = 0; q < 4; ++q) {
                int m = wm + mt * 16 + lk * 4 + q;
                int n = wn + nt * 16 + lr;
                T[m * 68 + n] = acc0[mt][nt][q] + acc1[mt][nt][q] * INV_SPLIT;
            }
    __syncthreads();

    {
        int rr = tid >> 2;                // out row 0..127
        int c0 = (tid & 3) * 16;          // 16 consecutive cols
        int m = mBase + rr;
        size_t o = (size_t)m * 256 + nBase + c0;
        float v[16];
        #pragma unroll
        for (int i = 0; i < 4; ++i) {
            float4 f = *(const float4*)&T[rr * 68 + c0 + i * 4];
            v[i * 4 + 0] = f.x; v[i * 4 + 1] = f.y;
            v[i * 4 + 2] = f.z; v[i * 4 + 3] = f.w;
        }
        if (bias) {
            #pragma unroll
            for (int i = 0; i < 4; ++i) {
                float4 bv = *(const float4*)(bias + nBase + c0 + i * 4);
                v[i * 4 + 0] += bv.x; v[i * 4 + 1] += bv.y;
                v[i * 4 + 2] += bv.z; v[i * 4 + 3] += bv.w;
            }
        }
        if (relu) {
            #pragma unroll
            for (int i = 0; i < 16; ++i) v[i] = fmaxf(v[i], 0.0f);
        }
        if (Shi) {
            #pragma unroll
            for (int j = 0; j < 2; ++j) {
                H8 sh, sl;
                sh.i4 = *(const int4*)(Shi + o + j * 8);
                sl.i4 = *(const int4*)(Slo + o + j * 8);
                #pragma unroll
                for (int u = 0; u < 8; ++u)
                    v[j * 8 + u] += fmaf((float)sl.h[u], INV_SPLIT, (float)sh.h[u]);
            }
        }
        if (Cf32) {
            #pragma unroll
            for (int i = 0; i < 4; ++i) {
                *(float4*)(Cf32 + o + i * 4) =
                    make_float4(v[i * 4], v[i * 4 + 1], v[i * 4 + 2], v[i * 4 + 3]);
            }
        } else {
            #pragma unroll
            for (int j = 0; j < 2; ++j) {
                H8 hh;
                #pragma unroll
                for (int u = 0; u < 8; ++u) hh.h[u] = (_Float16)v[j * 8 + u];
                *(int4*)(Chi + o + j * 8) = hh.i4;
            }
            if (lo_write) {
                #pragma unroll
                for (int j = 0; j < 2; ++j) {
                    H8 ll;
                    #pragma unroll
                    for (int u = 0; u < 8; ++u) {
                        float x = v[j * 8 + u];
                        ll.h[u] = (_Float16)((x - (float)(_Float16)x) * SPLIT_SCALE);
                    }
                    *(int4*)(Clo + o + j * 8) = ll.i4;
                }
            }
        }
    }
}

// ---------------------------------------------------------------------------
extern "C" void kernel_launch(void* const* d_in, const int* in_sizes, int n_in,
                              void* d_out, int out_size, void* d_ws, size_t ws_size,
                              hipStream_t stream)
{
    const float* x_in     = (const float*)d_in[0];
    const float* contacts = (const float*)d_in[1];
    const float* W_list   = (const float*)d_in[2];
    const float* dense_W  = (const float*)d_in[3];
    const float* dense_b  = (const float*)d_in[4];
    const float* final_W  = (const float*)d_in[5];
    const float* final_b  = (const float*)d_in[6];
    float* out = (float*)d_out;

    char* ws = (char*)d_ws;
    const size_t PL = (size_t)MROWS * DD;
    _Float16* pl[8];
    for (int i = 0; i < 8; ++i) pl[i] = (_Float16*)ws + (size_t)i * PL;
    char* p8 = ws + 8 * PL * sizeof(_Float16);
    int*   idx   = (int*)p8;
    int*   cnt   = (int*)(p8 + (size_t)MROWS * MAXNZ * sizeof(int));
    float* adiag = (float*)((char*)cnt + (size_t)MROWS * sizeof(int));
    _Float16* wt_hi = (_Float16*)((char*)adiag + (size_t)MROWS * sizeof(float));
    _Float16* wt_lo = wt_hi + (size_t)10 * 65536;

    setup_all<<<6160, 256, 0, stream>>>(W_list, dense_W, final_W, wt_hi, wt_lo,
                                        x_in, pl[0], pl[1],
                                        contacts, idx, cnt, adiag);

    dim3 gg(4, MROWS / 128);   // (4, 125) = 500 blocks x 512 threads
    int cur = 0;
    for (int l = 0; l < LL; ++l) {
        int oth = 1 - cur;
        _Float16 *x0h = pl[2 * cur], *x0l = pl[2 * cur + 1];
        _Float16 *yh  = pl[2 * oth], *yl  = pl[2 * oth + 1];
        _Float16 *xah = pl[4], *xal = pl[5];
        _Float16 *xbh = pl[6], *xbl = pl[7];
        // y = x0 @ W_l (hi out only — scores tolerate fp16)
        gemm16<<<gg, 512, 0, stream>>>(x0h, x0l,
                                       wt_hi + (size_t)l * 65536,
                                       wt_lo + (size_t)l * 65536,
                                       nullptr, nullptr, nullptr,
                                       yh, yl, nullptr, 0, 0);
        // sparse attention aggregate
        sparse_agg<<<MROWS / 4, 256, 0, stream>>>(yh, x0h, x0l, idx, cnt, adiag,
                                                  xah, xal);
        // dense 1 (relu)
        gemm16<<<gg, 512, 0, stream>>>(xah, xal,
                                       wt_hi + (size_t)(3 + l * 2) * 65536,
                                       wt_lo + (size_t)(3 + l * 2) * 65536,
                                       dense_b + (size_t)(l * 2 + 0) * 256,
                                       nullptr, nullptr,
                                       xbh, xbl, nullptr, 1, 1);
        // dense 2 (relu) + skip(x0) -> next X0
        gemm16<<<gg, 512, 0, stream>>>(xbh, xbl,
                                       wt_hi + (size_t)(4 + l * 2) * 65536,
                                       wt_lo + (size_t)(4 + l * 2) * 65536,
                                       dense_b + (size_t)(l * 2 + 1) * 256,
                                       x0h, x0l,
                                       yh, yl, nullptr, 1, 1);
        cur = oth;
    }
    // final projection -> fp32 d_out
    gemm16<<<gg, 512, 0, stream>>>(pl[2 * cur], pl[2 * cur + 1],
                                   wt_hi + (size_t)9 * 65536,
                                   wt_lo + (size_t)9 * 65536,
                                   final_b, nullptr, nullptr,
                                   nullptr, nullptr, out, 0, 0);
}

// Round 13
// 269.148 us; speedup vs baseline: 1.5269x; 1.0392x over previous
//
#include <hip/hip_runtime.h>

#define BB 16
#define NN 1000
#define DD 256
#define LL 3
#define MAXNZ 256
#define MROWS (BB * NN)
#define SPLIT_SCALE 2048.0f
#define INV_SPLIT 4.8828125e-4f

typedef _Float16 f16x8 __attribute__((ext_vector_type(8)));
typedef _Float16 f16x2 __attribute__((ext_vector_type(2)));
typedef float f32x4 __attribute__((ext_vector_type(4)));

union H8 { f16x8 v; f16x2 p[4]; _Float16 h[8]; int4 i4; unsigned int w[4]; };

#if defined(__has_builtin)
#if __has_builtin(__builtin_amdgcn_fdot2)
#define HAS_FDOT2 1
#endif
#endif

__device__ __forceinline__ float dot2f(f16x2 a, f16x2 b, float c) {
#ifdef HAS_FDOT2
    return __builtin_amdgcn_fdot2(a, b, c, false);
#else
    return fmaf((float)a[0], (float)b[0], fmaf((float)a[1], (float)b[1], c));
#endif
}

// acc_lo += (fp16)pk.lo * s;  acc_hi += (fp16)pk.hi * s   — single VALU op each
// (v_fma_mix_f32: op_sel_hi[0]=1 -> src0 is f16; op_sel[0] picks lo/hi half).
// Bit-exact vs cvt+fma (fp16 source is converted exactly).
__device__ __forceinline__ void fmix2(float& alo, float& ahi,
                                      unsigned int pk, float s) {
    asm("v_fma_mix_f32 %0, %1, %2, %0 op_sel:[0,0,0] op_sel_hi:[1,0,0]"
        : "+v"(alo) : "v"(pk), "v"(s));
    asm("v_fma_mix_f32 %0, %1, %2, %0 op_sel:[1,0,0] op_sel_hi:[1,0,0]"
        : "+v"(ahi) : "v"(pk), "v"(s));
}

// ---------------------------------------------------------------------------
// Kernel 0 (fused setup): [0,160) convert_w, [160,2160) convert_x,
// [2160,6160) build_sparse.
// ---------------------------------------------------------------------------
__global__ __launch_bounds__(256) void setup_all(
    const float* __restrict__ W_list, const float* __restrict__ dense_W,
    const float* __restrict__ final_W,
    _Float16* __restrict__ wt_hi, _Float16* __restrict__ wt_lo,
    const float* __restrict__ x_in,
    _Float16* __restrict__ xh, _Float16* __restrict__ xl,
    const float* __restrict__ contacts,
    int* __restrict__ idx, int* __restrict__ cnt, float* __restrict__ adiag)
{
    __shared__ float T[64][68];
    int bid = blockIdx.x;
    int t = threadIdx.x;

    if (bid < 160) {
        int mat = bid >> 4;
        int tile = bid & 15;
        int tk = (tile >> 2) * 64, tn = (tile & 3) * 64;
        const float* src = (mat < 3) ? (W_list + (size_t)mat * 65536)
                         : (mat < 9) ? (dense_W + (size_t)(mat - 3) * 65536)
                                     : final_W;
        {
            int k = t >> 2, nc = (t & 3) * 16;
            const float* sp = src + (size_t)(tk + k) * 256 + tn + nc;
            *(float4*)&T[k][nc + 0]  = *(const float4*)(sp + 0);
            *(float4*)&T[k][nc + 4]  = *(const float4*)(sp + 4);
            *(float4*)&T[k][nc + 8]  = *(const float4*)(sp + 8);
            *(float4*)&T[k][nc + 12] = *(const float4*)(sp + 12);
        }
        __syncthreads();
        int n = t >> 2, kc = (t & 3) * 16;
        H8 hh0, hh1, ll0, ll1;
        #pragma unroll
        for (int i = 0; i < 16; ++i) {
            float x = T[kc + i][n];
            _Float16 hi = (_Float16)x;
            _Float16 lo = (_Float16)((x - (float)hi) * SPLIT_SCALE);
            if (i < 8) { hh0.h[i] = hi; ll0.h[i] = lo; }
            else       { hh1.h[i - 8] = hi; ll1.h[i - 8] = lo; }
        }
        size_t o = (size_t)mat * 65536 + (size_t)(tn + n) * 256 + tk + kc;
        *(int4*)(wt_hi + o)     = hh0.i4;
        *(int4*)(wt_hi + o + 8) = hh1.i4;
        *(int4*)(wt_lo + o)     = ll0.i4;
        *(int4*)(wt_lo + o + 8) = ll1.i4;
    } else if (bid < 2160) {
        size_t gid = (size_t)(bid - 160) * 256 + t;
        const float* p = x_in + gid * 8;
        float4 a = *(const float4*)p;
        float4 b = *(const float4*)(p + 4);
        float xs[8] = {a.x, a.y, a.z, a.w, b.x, b.y, b.z, b.w};
        H8 hh, ll;
        #pragma unroll
        for (int i = 0; i < 8; ++i) {
            _Float16 h = (_Float16)xs[i];
            hh.h[i] = h;
            ll.h[i] = (_Float16)((xs[i] - (float)h) * SPLIT_SCALE);
        }
        *(int4*)(xh + gid * 8) = hh.i4;
        *(int4*)(xl + gid * 8) = ll.i4;
    } else {
        int wave = (int)(((size_t)(bid - 2160) * 256 + t) >> 6);
        int lane = t & 63;
        int b = wave / NN;
        int i = wave - b * NN;
        const float* row = contacts + (size_t)b * NN * NN + (size_t)i * NN;
        int* out = idx + (size_t)wave * MAXNZ;
        int count = 0;
        for (int j0 = 0; j0 < NN; j0 += 64) {
            int j = j0 + lane;
            float v = (j < NN) ? row[j] : 0.0f;
            bool p = (v != 0.0f) && (j != i);
            unsigned long long bal = __ballot(p);
            if (p) {
                int pre = __popcll(bal & ((1ull << lane) - 1ull));
                out[count + pre] = j;
            }
            count += __popcll(bal);
        }
        if (lane == 0) {
            cnt[wave] = count;
            adiag[wave] = row[i] + 1.0f;
        }
    }
}

// ---------------------------------------------------------------------------
// Kernel 2: sparse attention aggregate v8 = v7 + v_fma_mix accumulation.
// 1 wave per row; 16-lane group holds full 256-dim row (8+8 halves/lane).
// Two independent neighbor streams per iteration (8 neighbors/wave-iter).
// ---------------------------------------------------------------------------
__global__ __launch_bounds__(256, 3) void sparse_agg(
    const _Float16* __restrict__ yhi,
    const _Float16* __restrict__ xhi, const _Float16* __restrict__ xlo,
    const int* __restrict__ idx, const int* __restrict__ cnt,
    const float* __restrict__ adiag,
    _Float16* __restrict__ ohi, _Float16* __restrict__ olo)
{
    int bid = blockIdx.x;
    int xcd = bid & 7;
    int chunk = bid >> 3;
    int row = xcd * 2000 + chunk * 4 + (int)(threadIdx.x >> 6);
    row = __builtin_amdgcn_readfirstlane(row);
    int lane = threadIdx.x & 63;
    int g = lane >> 4, s = lane & 15;
    int b = row / NN;

    const _Float16* yp = yhi + (size_t)row * DD + s * 8;
    H8 yh0, yh1;
    yh0.i4 = *(const int4*)yp;
    yh1.i4 = *(const int4*)(yp + 128);

    const _Float16* xph = xhi + (size_t)row * DD + s * 8;
    const _Float16* xpl = xlo + (size_t)row * DD + s * 8;
    H8 xih0, xih1, xil0, xil1;
    xih0.i4 = *(const int4*)xph;       xih1.i4 = *(const int4*)(xph + 128);
    xil0.i4 = *(const int4*)xpl;       xil1.i4 = *(const int4*)(xpl + 128);
    float xi[16];
    #pragma unroll
    for (int u = 0; u < 8; ++u) {
        xi[u]     = fmaf((float)xil0.h[u], INV_SPLIT, (float)xih0.h[u]);
        xi[8 + u] = fmaf((float)xil1.h[u], INV_SPLIT, (float)xih1.h[u]);
    }
    const _Float16* xb = xhi + (size_t)b * NN * DD;

    float p = 0.0f;
    #pragma unroll
    for (int u = 0; u < 8; ++u) {
        p = fmaf((float)yh0.h[u], xi[u], p);
        p = fmaf((float)yh1.h[u], xi[8 + u], p);
    }
    p += __shfl_xor(p, 1); p += __shfl_xor(p, 2);
    p += __shfl_xor(p, 4); p += __shfl_xor(p, 8);
    float wd = (g == 0) ? (__expf(p) + 1e-5f) * adiag[row] : 0.0f;
    float denom = wd;
    float acc[16];
    #pragma unroll
    for (int u = 0; u < 16; ++u) acc[u] = wd * xi[u];

    const int c = cnt[row];
    const int* ip = idx + (size_t)row * MAXNZ;
    const int iters = (c + 7) >> 3;

    int jA1, jB1;
    H8 vA0, vA1, vB0, vB1;
    {
        int ja = (g < c) ? ip[g] : 0;
        int jb = (4 + g < c) ? ip[4 + g] : 0;
        jA1 = (8 + g < c) ? ip[8 + g] : 0;
        jB1 = (12 + g < c) ? ip[12 + g] : 0;
        const _Float16* pa = xb + (size_t)ja * DD + s * 8;
        vA0.i4 = *(const int4*)pa;
        vA1.i4 = *(const int4*)(pa + 128);
        const _Float16* pb = xb + (size_t)jb * DD + s * 8;
        vB0.i4 = *(const int4*)pb;
        vB1.i4 = *(const int4*)(pb + 128);
    }

    for (int t = 0; t < iters; ++t) {
        int k2a = (t + 2) * 8 + g;
        int k2b = k2a + 4;
        int jA2 = (k2a < c) ? ip[k2a] : 0;
        int jB2 = (k2b < c) ? ip[k2b] : 0;
        H8 mA0, mA1, mB0, mB1;
        const _Float16* pa = xb + (size_t)jA1 * DD + s * 8;
        mA0.i4 = *(const int4*)pa;
        mA1.i4 = *(const int4*)(pa + 128);
        const _Float16* pb = xb + (size_t)jB1 * DD + s * 8;
        mB0.i4 = *(const int4*)pb;
        mB1.i4 = *(const int4*)(pb + 128);

        bool vokA = t * 8 + g < c;
        bool vokB = t * 8 + 4 + g < c;

        float qa0 = 0.0f, qa1 = 0.0f, qb0 = 0.0f, qb1 = 0.0f;
        #pragma unroll
        for (int i = 0; i < 4; ++i) {
            qa0 = dot2f(yh0.p[i], vA0.p[i], qa0);
            qa1 = dot2f(yh1.p[i], vA1.p[i], qa1);
            qb0 = dot2f(yh0.p[i], vB0.p[i], qb0);
            qb1 = dot2f(yh1.p[i], vB1.p[i], qb1);
        }
        float qa = qa0 + qa1, qb = qb0 + qb1;
        qa += __shfl_xor(qa, 1); qb += __shfl_xor(qb, 1);
        qa += __shfl_xor(qa, 2); qb += __shfl_xor(qb, 2);
        qa += __shfl_xor(qa, 4); qb += __shfl_xor(qb, 4);
        qa += __shfl_xor(qa, 8); qb += __shfl_xor(qb, 8);
        float wa = vokA ? __expf(qa) : 0.0f;
        float wb = vokB ? __expf(qb) : 0.0f;
        denom += wa + wb;
        // packed fp16-source accumulation: one v_fma_mix_f32 per element
        #pragma unroll
        for (int i = 0; i < 4; ++i) {
            fmix2(acc[2 * i],     acc[2 * i + 1],     vA0.w[i], wa);
            fmix2(acc[8 + 2 * i], acc[8 + 2 * i + 1], vA1.w[i], wa);
        }
        #pragma unroll
        for (int i = 0; i < 4; ++i) {
            fmix2(acc[2 * i],     acc[2 * i + 1],     vB0.w[i], wb);
            fmix2(acc[8 + 2 * i], acc[8 + 2 * i + 1], vB1.w[i], wb);
        }

        vA0 = mA0; vA1 = mA1; vB0 = mB0; vB1 = mB1;
        jA1 = jA2; jB1 = jB2;
    }

#define XG(x) x += __shfl_xor(x, 16); x += __shfl_xor(x, 32);
    XG(denom);
    #pragma unroll
    for (int u = 0; u < 16; ++u) { XG(acc[u]) }
#undef XG

    float inv = 1.0f / denom;
    int half = (g & 1) * 8;
    H8 st;
    #pragma unroll
    for (int i = 0; i < 8; ++i) {
        float x = acc[half + i] * inv;
        _Float16 h = (_Float16)x;
        st.h[i] = (g & 2) ? (_Float16)((x - (float)h) * SPLIT_SCALE) : h;
    }
    _Float16* dst = ((g & 2) ? olo : ohi) + (size_t)row * DD + (g & 1) * 128 + s * 8;
    *(int4*)dst = st.i4;
}

// ---------------------------------------------------------------------------
// Kernel 3: split-fp16 MFMA GEMM v8 (round-12, frozen).
// BM=128, BN=64, BK=64; 512 threads = 8 waves (4m x 2n), wave tile 32x32.
// ---------------------------------------------------------------------------
__global__ __launch_bounds__(512, 4) void gemm16(
    const _Float16* __restrict__ Ahi, const _Float16* __restrict__ Alo,
    const _Float16* __restrict__ Bhi, const _Float16* __restrict__ Blo,
    const float* __restrict__ bias,
    const _Float16* __restrict__ Shi, const _Float16* __restrict__ Slo,
    _Float16* __restrict__ Chi, _Float16* __restrict__ Clo,
    float* __restrict__ Cf32, int relu, int lo_write)
{
    __shared__ __align__(16) char smem[49152];
    char* Ah = smem;              // [128 m][64 k] halves swz, 16 KB
    char* Al = smem + 16384;
    char* Bh = smem + 32768;      // [64 n][64 k], 8 KB
    char* Bl = smem + 40960;

    int tid = threadIdx.x;
    int mBase = blockIdx.y * 128;
    int nBase = blockIdx.x * 64;

    int ra = tid >> 2, ka = (tid & 3) * 16;
    const _Float16* gAh = Ahi + (size_t)(mBase + ra) * 256 + ka;
    const _Float16* gAl = Alo + (size_t)(mBase + ra) * 256 + ka;
    int sbA = ra * 128 + ka * 2, swzA = (ra & 7) << 4;
    int rb = tid >> 3, kbb = (tid & 7) * 8;
    const _Float16* gBh = Bhi + (size_t)(nBase + rb) * 256 + kbb;
    const _Float16* gBl = Blo + (size_t)(nBase + rb) * 256 + kbb;
    int sbB = rb * 128 + kbb * 2, swzB = (rb & 7) << 4;

    int l = tid & 63, wv = tid >> 6;
    int wm = (wv & 3) * 32, wn = (wv >> 2) * 32;
    int lr = l & 15, lk = l >> 4;

    f32x4 acc0[2][2] = {};
    f32x4 acc1[2][2] = {};

    int4 rA0, rA1, rA2, rA3, rB0, rB1;
#define LOADG(kb) \
    rA0 = *(const int4*)(gAh + (kb));     rA1 = *(const int4*)(gAh + (kb) + 8); \
    rA2 = *(const int4*)(gAl + (kb));     rA3 = *(const int4*)(gAl + (kb) + 8); \
    rB0 = *(const int4*)(gBh + (kb));     rB1 = *(const int4*)(gBl + (kb));

    LOADG(0)

    #pragma unroll
    for (int kb = 0; kb < 256; kb += 64) {
        __syncthreads();
        *(int4*)(Ah + ((sbA +  0) ^ swzA)) = rA0;
        *(int4*)(Ah + ((sbA + 16) ^ swzA)) = rA1;
        *(int4*)(Al + ((sbA +  0) ^ swzA)) = rA2;
        *(int4*)(Al + ((sbA + 16) ^ swzA)) = rA3;
        *(int4*)(Bh + (sbB ^ swzB)) = rB0;
        *(int4*)(Bl + (sbB ^ swzB)) = rB1;
        __syncthreads();

        if (kb < 192) { LOADG(kb + 64) }

        #pragma unroll
        for (int kk = 0; kk < 2; ++kk) {
            int kby = kk * 64 + lk * 16;
            f16x8 fah[2], fal[2], fbh[2], fbl[2];
            #pragma unroll
            for (int mt = 0; mt < 2; ++mt) {
                int ml = wm + mt * 16 + lr;
                int off = (ml * 128 + kby) ^ ((ml & 7) << 4);
                fah[mt] = *(const f16x8*)(Ah + off);
                fal[mt] = *(const f16x8*)(Al + off);
            }
            #pragma unroll
            for (int nt = 0; nt < 2; ++nt) {
                int nl = wn + nt * 16 + lr;
                int off = (nl * 128 + kby) ^ ((nl & 7) << 4);
                fbh[nt] = *(const f16x8*)(Bh + off);
                fbl[nt] = *(const f16x8*)(Bl + off);
            }
            #pragma unroll
            for (int mt = 0; mt < 2; ++mt)
                #pragma unroll
                for (int nt = 0; nt < 2; ++nt) {
                    acc0[mt][nt] = __builtin_amdgcn_mfma_f32_16x16x32_f16(
                        fah[mt], fbh[nt], acc0[mt][nt], 0, 0, 0);
                    acc1[mt][nt] = __builtin_amdgcn_mfma_f32_16x16x32_f16(
                        fah[mt], fbl[nt], acc1[mt][nt], 0, 0, 0);
                    acc1[mt][nt] = __builtin_amdgcn_mfma_f32_16x16x32_f16(
                        fal[mt], fbh[nt], acc1[mt][nt], 0, 0, 0);
                }
        }
    }
#undef LOADG

    __syncthreads();
    float* T = (float*)smem;              // [128][68] fp32
    #pragma unroll
    for (int mt = 0; mt < 2; ++mt)
        #pragma unroll
        for (int nt = 0; nt < 2; ++nt)
            #pragma unroll
            for (int q = 0; q < 4; ++q) {
                int m = wm + mt * 16 + lk * 4 + q;
                int n = wn + nt * 16 + lr;
                T[m * 68 + n] = acc0[mt][nt][q] + acc1[mt][nt][q] * INV_SPLIT;
            }
    __syncthreads();

    {
        int rr = tid >> 2;
        int c0 = (tid & 3) * 16;
        int m = mBase + rr;
        size_t o = (size_t)m * 256 + nBase + c0;
        float v[16];
        #pragma unroll
        for (int i = 0; i < 4; ++i) {
            float4 f = *(const float4*)&T[rr * 68 + c0 + i * 4];
            v[i * 4 + 0] = f.x; v[i * 4 + 1] = f.y;
            v[i * 4 + 2] = f.z; v[i * 4 + 3] = f.w;
        }
        if (bias) {
            #pragma unroll
            for (int i = 0; i < 4; ++i) {
                float4 bv = *(const float4*)(bias + nBase + c0 + i * 4);
                v[i * 4 + 0] += bv.x; v[i * 4 + 1] += bv.y;
                v[i * 4 + 2] += bv.z; v[i * 4 + 3] += bv.w;
            }
        }
        if (relu) {
            #pragma unroll
            for (int i = 0; i < 16; ++i) v[i] = fmaxf(v[i], 0.0f);
        }
        if (Shi) {
            #pragma unroll
            for (int j = 0; j < 2; ++j) {
                H8 sh, sl;
                sh.i4 = *(const int4*)(Shi + o + j * 8);
                sl.i4 = *(const int4*)(Slo + o + j * 8);
                #pragma unroll
                for (int u = 0; u < 8; ++u)
                    v[j * 8 + u] += fmaf((float)sl.h[u], INV_SPLIT, (float)sh.h[u]);
            }
        }
        if (Cf32) {
            #pragma unroll
            for (int i = 0; i < 4; ++i) {
                *(float4*)(Cf32 + o + i * 4) =
                    make_float4(v[i * 4], v[i * 4 + 1], v[i * 4 + 2], v[i * 4 + 3]);
            }
        } else {
            #pragma unroll
            for (int j = 0; j < 2; ++j) {
                H8 hh;
                #pragma unroll
                for (int u = 0; u < 8; ++u) hh.h[u] = (_Float16)v[j * 8 + u];
                *(int4*)(Chi + o + j * 8) = hh.i4;
            }
            if (lo_write) {
                #pragma unroll
                for (int j = 0; j < 2; ++j) {
                    H8 ll;
                    #pragma unroll
                    for (int u = 0; u < 8; ++u) {
                        float x = v[j * 8 + u];
                        ll.h[u] = (_Float16)((x - (float)(_Float16)x) * SPLIT_SCALE);
                    }
                    *(int4*)(Clo + o + j * 8) = ll.i4;
                }
            }
        }
    }
}

// ---------------------------------------------------------------------------
extern "C" void kernel_launch(void* const* d_in, const int* in_sizes, int n_in,
                              void* d_out, int out_size, void* d_ws, size_t ws_size,
                              hipStream_t stream)
{
    const float* x_in     = (const float*)d_in[0];
    const float* contacts = (const float*)d_in[1];
    const float* W_list   = (const float*)d_in[2];
    const float* dense_W  = (const float*)d_in[3];
    const float* dense_b  = (const float*)d_in[4];
    const float* final_W  = (const float*)d_in[5];
    const float* final_b  = (const float*)d_in[6];
    float* out = (float*)d_out;

    char* ws = (char*)d_ws;
    const size_t PL = (size_t)MROWS * DD;
    _Float16* pl[8];
    for (int i = 0; i < 8; ++i) pl[i] = (_Float16*)ws + (size_t)i * PL;
    char* p8 = ws + 8 * PL * sizeof(_Float16);
    int*   idx   = (int*)p8;
    int*   cnt   = (int*)(p8 + (size_t)MROWS * MAXNZ * sizeof(int));
    float* adiag = (float*)((char*)cnt + (size_t)MROWS * sizeof(int));
    _Float16* wt_hi = (_Float16*)((char*)adiag + (size_t)MROWS * sizeof(float));
    _Float16* wt_lo = wt_hi + (size_t)10 * 65536;

    setup_all<<<6160, 256, 0, stream>>>(W_list, dense_W, final_W, wt_hi, wt_lo,
                                        x_in, pl[0], pl[1],
                                        contacts, idx, cnt, adiag);

    dim3 gg(4, MROWS / 128);   // (4, 125) = 500 blocks x 512 threads
    int cur = 0;
    for (int l = 0; l < LL; ++l) {
        int oth = 1 - cur;
        _Float16 *x0h = pl[2 * cur], *x0l = pl[2 * cur + 1];
        _Float16 *yh  = pl[2 * oth], *yl  = pl[2 * oth + 1];
        _Float16 *xah = pl[4], *xal = pl[5];
        _Float16 *xbh = pl[6], *xbl = pl[7];
        // y = x0 @ W_l (hi out only — scores tolerate fp16)
        gemm16<<<gg, 512, 0, stream>>>(x0h, x0l,
                                       wt_hi + (size_t)l * 65536,
                                       wt_lo + (size_t)l * 65536,
                                       nullptr, nullptr, nullptr,
                                       yh, yl, nullptr, 0, 0);
        // sparse attention aggregate
        sparse_agg<<<MROWS / 4, 256, 0, stream>>>(yh, x0h, x0l, idx, cnt, adiag,
                                                  xah, xal);
        // dense 1 (relu)
        gemm16<<<gg, 512, 0, stream>>>(xah, xal,
                                       wt_hi + (size_t)(3 + l * 2) * 65536,
                                       wt_lo + (size_t)(3 + l * 2) * 65536,
                                       dense_b + (size_t)(l * 2 + 0) * 256,
                                       nullptr, nullptr,
                                       xbh, xbl, nullptr, 1, 1);
        // dense 2 (relu) + skip(x0) -> next X0
        gemm16<<<gg, 512, 0, stream>>>(xbh, xbl,
                                       wt_hi + (size_t)(4 + l * 2) * 65536,
                                       wt_lo + (size_t)(4 + l * 2) * 65536,
                                       dense_b + (size_t)(l * 2 + 1) * 256,
                                       x0h, x0l,
                                       yh, yl, nullptr, 1, 1);
        cur = oth;
    }
    // final projection -> fp32 d_out
    gemm16<<<gg, 512, 0, stream>>>(pl[2 * cur], pl[2 * cur + 1],
                                   wt_hi + (size_t)9 * 65536,
                                   wt_lo + (size_t)9 * 65536,
                                   final_b, nullptr, nullptr,
                                   nullptr, nullptr, out, 0, 0);
}